// Round 1
// baseline (6234.769 us; speedup 1.0000x reference)
//
#include <hip/hip_runtime.h>
#include <hip/hip_bf16.h>
#include <math.h>

// TransformerDecoder2dLayer on MI355X (gfx950).
// Pipeline:
//  tcast x10 (W -> W^T bf16) ; tsproj x4 (ts K/V projections)
//  [spatial]  QKV gemm (fused, A=x f32) -> attn (VALU) -> O-proj+residual -> norm1(+transpose)
//  [temporal] QKV gemm (A=x1t f32)      -> attn (VALU) -> O-proj+residual -> norm2(+transpose)
//  [FF]       gelu gemm chunks -> accumulate gemm chunks (+x2 residual) -> norm3
// K/V bf16 buffers live inside d_out (2 x M*512 bf16 == M*512 f32 bytes), dead by the
// time O-proj writes d_out as f32.

#define F_DIM 120
#define B_DIM 64
#define J_DIM 22
#define H_DIM 4
#define M_TOK (F_DIM * B_DIM * J_DIM) // 168960

#define DEV static __device__ __forceinline__

typedef short bf16x8 __attribute__((ext_vector_type(8)));
typedef float f32x4 __attribute__((ext_vector_type(4)));

struct __align__(8) us4 { unsigned short x, y, z, w; };

DEV unsigned short f2b(float f) {
  unsigned u = __float_as_uint(f);
  u += 0x7fffu + ((u >> 16) & 1u);
  return (unsigned short)(u >> 16);
}
DEV float b2f(unsigned short u) { return __uint_as_float(((unsigned)u) << 16); }

enum { EPI_QKV = 0, EPI_GELU = 1, EPI_RES = 2, EPI_ACC = 3 };

// ---------------------------------------------------------------------------
// Weight transpose + cast: W (K x N f32, row-major) -> WT (N x K bf16)
__global__ __launch_bounds__(256)
void tcast_k(const float* __restrict__ W, unsigned short* __restrict__ WT, int K, int N) {
  __shared__ float t[32][33];
  const int n0 = blockIdx.x * 32, k0 = blockIdx.y * 32;
  const int tx = threadIdx.x, ty = threadIdx.y;
#pragma unroll
  for (int i = 0; i < 4; ++i)
    t[ty + i * 8][tx] = W[(size_t)(k0 + ty + i * 8) * N + n0 + tx];
  __syncthreads();
#pragma unroll
  for (int i = 0; i < 4; ++i)
    WT[(size_t)(n0 + ty + i * 8) * K + k0 + tx] = f2b(t[tx][ty + i * 8]);
}

// ---------------------------------------------------------------------------
// ts-token K/V projection: out[b][n] = sum_k ts[b][k] * W[k][n] + bias[n]  (bf16 out)
__global__ __launch_bounds__(256)
void tsproj_k(const float* __restrict__ ts, const float* __restrict__ W,
              const float* __restrict__ bias, unsigned short* __restrict__ out) {
  __shared__ float tsr[512];
  const int b = blockIdx.x, tid = threadIdx.x;
  for (int i = tid; i < 512; i += 256) tsr[i] = ts[b * 512 + i];
  __syncthreads();
  const int n0 = tid, n1 = tid + 256;
  float a0 = bias[n0], a1 = bias[n1];
  for (int k = 0; k < 512; ++k) {
    const float t = tsr[k];
    a0 += t * W[(size_t)k * 512 + n0];
    a1 += t * W[(size_t)k * 512 + n1];
  }
  out[b * 512 + n0] = f2b(a0);
  out[b * 512 + n1] = f2b(a1);
}

// ---------------------------------------------------------------------------
// Tiled MFMA GEMM: C(M x Ngrid*128) = A(M x nk) @ W(nk x N), W given as WT (N x nk bf16).
// 128x128 tile, BK=32, 4 waves, each wave 64x64 (4x4 of 16x16x32 bf16 MFMA).
// A staged to LDS with optional f32->bf16 cast; B tiles staged identically (WT rows).
template<bool AF32, int EPI>
__global__ __launch_bounds__(256)
void gemm_k(const void* __restrict__ Ap, const unsigned short* __restrict__ Wt,
            const float* __restrict__ b0, const float* __restrict__ b1, const float* __restrict__ b2,
            const float* __restrict__ res, float* __restrict__ outF,
            unsigned short* __restrict__ o0, unsigned short* __restrict__ o1, unsigned short* __restrict__ o2,
            int lda, int ldw, int ldo, int nk, float scale) {
  __shared__ unsigned short As[128][40];
  __shared__ unsigned short Bs[128][40];
  const int tid = threadIdx.x;
  const int nbase = blockIdx.x * 128;   // ntile on x: consecutive blocks share A tile (L2)
  const int mbase = blockIdx.y * 128;
  const int lane = tid & 63;
  const int w = tid >> 6;
  const int wr = (w >> 1) * 64;
  const int wc = (w & 1) * 64;
  const int l15 = lane & 15;
  const int lhi = lane >> 4;

  const float* Af = (const float*)Ap;
  const unsigned short* Ab = (const unsigned short*)Ap;

  float4 ra[4];
  us4 ra16[4];
  us4 rb[4];

  auto loadAB = [&](int kt) {
#pragma unroll
    for (int i = 0; i < 4; ++i) {
      const int g = i * 256 + tid;
      const int r = g >> 3;
      const int c = (g & 7) << 2;
      if constexpr (AF32)
        ra[i] = *(const float4*)(Af + (size_t)(mbase + r) * lda + kt + c);
      else
        ra16[i] = *(const us4*)(Ab + (size_t)(mbase + r) * lda + kt + c);
      rb[i] = *(const us4*)(Wt + (size_t)(nbase + r) * ldw + kt + c);
    }
  };
  auto storeAB = [&]() {
#pragma unroll
    for (int i = 0; i < 4; ++i) {
      const int g = i * 256 + tid;
      const int r = g >> 3;
      const int c = (g & 7) << 2;
      us4 ua;
      if constexpr (AF32) {
        ua.x = f2b(ra[i].x); ua.y = f2b(ra[i].y); ua.z = f2b(ra[i].z); ua.w = f2b(ra[i].w);
      } else ua = ra16[i];
      *(us4*)&As[r][c] = ua;
      *(us4*)&Bs[r][c] = rb[i];
    }
  };

  f32x4 acc[4][4] = {};

  const int KT = nk >> 5;
  loadAB(0);
  storeAB();
  __syncthreads();
  for (int t = 0; t < KT; ++t) {
    if (t + 1 < KT) loadAB((t + 1) << 5);  // prefetch to regs, overlaps MFMA below
    bf16x8 afr[4], bfr[4];
    const int klo = lhi << 3;
#pragma unroll
    for (int i = 0; i < 4; ++i) afr[i] = *(const bf16x8*)&As[wr + i * 16 + l15][klo];
#pragma unroll
    for (int j = 0; j < 4; ++j) bfr[j] = *(const bf16x8*)&Bs[wc + j * 16 + l15][klo];
#pragma unroll
    for (int i = 0; i < 4; ++i)
#pragma unroll
      for (int j = 0; j < 4; ++j)
        acc[i][j] = __builtin_amdgcn_mfma_f32_16x16x32_bf16(afr[i], bfr[j], acc[i][j], 0, 0, 0);
    __syncthreads();
    if (t + 1 < KT) { storeAB(); __syncthreads(); }
  }

#pragma unroll
  for (int i = 0; i < 4; ++i) {
#pragma unroll
    for (int j = 0; j < 4; ++j) {
      const int row0 = mbase + wr + i * 16 + (lhi << 2);
      const int col = nbase + wc + j * 16 + l15;
#pragma unroll
      for (int q = 0; q < 4; ++q) {
        float v = acc[i][j][q];
        const int row = row0 + q;
        if constexpr (EPI == EPI_QKV) {
          const int seg = col >> 9;
          const int cl = col & 511;
          const float* bs = (seg == 0) ? b0 : (seg == 1) ? b1 : b2;
          unsigned short* ob = (seg == 0) ? o0 : (seg == 1) ? o1 : o2;
          const float sc = (seg == 0) ? scale : 1.f;
          v = (v + bs[cl]) * sc;
          ob[(size_t)row * 512 + cl] = f2b(v);
        } else if constexpr (EPI == EPI_GELU) {
          v += b0[col];
          v = 0.5f * v * (1.f + erff(v * 0.70710678118654752f));
          o0[(size_t)row * ldo + col] = f2b(v);
        } else if constexpr (EPI == EPI_RES) {
          const size_t off = (size_t)row * 512 + col;
          v += b0[col] + res[off];
          outF[off] = v;
        } else { // EPI_ACC
          const size_t off = (size_t)row * 512 + col;
          outF[off] = v + outF[off];
        }
      }
    }
  }
}

// ---------------------------------------------------------------------------
// VALU attention. Per block: one (instance, head, q-tile). Keys = [ts ; L tokens].
// K and Q (bf16) + scores in LDS (< 64KB); V read through L1/L2.
// Output written in-place over the Q buffer (Q fully consumed into LDS first).
template<int QT, int LK, int LKP, int TPB>
__global__ __launch_bounds__(TPB)
void attn_k(const unsigned short* __restrict__ Qb, const unsigned short* __restrict__ Kb,
            const unsigned short* __restrict__ Vb, const unsigned short* __restrict__ kts,
            const unsigned short* __restrict__ vts, unsigned short* __restrict__ Ob) {
  constexpr int L = LK - 1;
  __shared__ unsigned short Ks[LK][132];
  __shared__ unsigned short Qs[QT][132];
  __shared__ float Sm[QT][LKP];

  const int tid = threadIdx.x;
  const int inst = blockIdx.x >> 2;  // / H_DIM
  const int h = blockIdx.x & 3;
  const int q0 = blockIdx.y * QT;
  const int b = inst & (B_DIM - 1);
  const size_t rowbase = (size_t)inst * L;
  const int hoff = h * 128;

  for (int e = tid; e < LK * 128; e += TPB) {
    const int r = e >> 7, d = e & 127;
    Ks[r][d] = (r == 0) ? kts[b * 512 + hoff + d]
                        : Kb[(rowbase + (r - 1)) * 512 + hoff + d];
  }
  for (int e = tid; e < QT * 128; e += TPB) {
    const int qi = e >> 7, d = e & 127;
    Qs[qi][d] = Qb[(rowbase + q0 + qi) * 512 + hoff + d];
  }
  __syncthreads();

  // scores (Q was pre-scaled by 1/sqrt(dk) in the projection epilogue)
  for (int pp = tid; pp < QT * LK; pp += TPB) {
    const int q = pp / LK, k = pp % LK;
    float acc = 0.f;
#pragma unroll 8
    for (int d4 = 0; d4 < 32; ++d4) {
      const us4 qq = *(const us4*)&Qs[q][d4 * 4];
      const us4 kk = *(const us4*)&Ks[k][d4 * 4];
      acc += b2f(qq.x) * b2f(kk.x) + b2f(qq.y) * b2f(kk.y)
           + b2f(qq.z) * b2f(kk.z) + b2f(qq.w) * b2f(kk.w);
    }
    Sm[q][k] = acc;
  }
  __syncthreads();

  if (tid < QT) {
    float m = -1e30f;
    for (int k = 0; k < LK; ++k) m = fmaxf(m, Sm[tid][k]);
    float s = 0.f;
    for (int k = 0; k < LK; ++k) { const float e = __expf(Sm[tid][k] - m); Sm[tid][k] = e; s += e; }
    const float inv = 1.f / s;
    for (int k = 0; k < LK; ++k) Sm[tid][k] *= inv;
  }
  __syncthreads();

  const unsigned short* vts_row = vts + b * 512 + hoff;
  for (int u = tid; u < QT * 32; u += TPB) {
    const int q = u >> 5, d4 = (u & 31) << 2;
    float a0, a1, a2, a3;
    {
      const float s = Sm[q][0];
      const us4 vv = *(const us4*)&vts_row[d4];
      a0 = s * b2f(vv.x); a1 = s * b2f(vv.y); a2 = s * b2f(vv.z); a3 = s * b2f(vv.w);
    }
    for (int k = 1; k < LK; ++k) {
      const float s = Sm[q][k];
      const us4 vv = *(const us4*)&Vb[(rowbase + (k - 1)) * 512 + hoff + d4];
      a0 += s * b2f(vv.x); a1 += s * b2f(vv.y); a2 += s * b2f(vv.z); a3 += s * b2f(vv.w);
    }
    us4 o; o.x = f2b(a0); o.y = f2b(a1); o.z = f2b(a2); o.w = f2b(a3);
    *(us4*)&Ob[(rowbase + q0 + q) * 512 + hoff + d4] = o;
  }
}

// ---------------------------------------------------------------------------
// Row norm (torch.std semantics: ddof=1, eps added to sd), fused layout transpose.
// mode 0: identity; mode 1: (F,B,J)->(J,B,F); mode 2: (J,B,F)->(F,B,J)
__global__ __launch_bounds__(64)
void norm_k(const float* __restrict__ in, float* __restrict__ out,
            const float* __restrict__ ga, const float* __restrict__ gb, const int mode) {
  const int r = blockIdx.x;
  const int lane = threadIdx.x;
  const float* row = in + (size_t)r * 512;
  const float4 v0 = *(const float4*)&row[lane * 4];
  const float4 v1 = *(const float4*)&row[256 + lane * 4];
  float s = v0.x + v0.y + v0.z + v0.w + v1.x + v1.y + v1.z + v1.w;
  float ss = v0.x * v0.x + v0.y * v0.y + v0.z * v0.z + v0.w * v0.w
           + v1.x * v1.x + v1.y * v1.y + v1.z * v1.z + v1.w * v1.w;
#pragma unroll
  for (int m = 1; m < 64; m <<= 1) { s += __shfl_xor(s, m, 64); ss += __shfl_xor(ss, m, 64); }
  const float mean = s * (1.f / 512.f);
  const float var = (ss - 512.f * mean * mean) * (1.f / 511.f);
  const float inv = 1.f / (sqrtf(fmaxf(var, 0.f)) + 1e-6f);
  int ro;
  if (mode == 0) ro = r;
  else if (mode == 1) {
    const int f = r / (B_DIM * J_DIM);
    const int bb = (r / J_DIM) % B_DIM;
    const int j = r % J_DIM;
    ro = (j * B_DIM + bb) * F_DIM + f;
  } else {
    const int j = r / (B_DIM * F_DIM);
    const int bb = (r / F_DIM) % B_DIM;
    const int f = r % F_DIM;
    ro = (f * B_DIM + bb) * J_DIM + j;
  }
  const float4 g0 = *(const float4*)&ga[lane * 4];
  const float4 g1 = *(const float4*)&ga[256 + lane * 4];
  const float4 h0 = *(const float4*)&gb[lane * 4];
  const float4 h1 = *(const float4*)&gb[256 + lane * 4];
  float4 y0, y1;
  y0.x = g0.x * (v0.x - mean) * inv + h0.x;
  y0.y = g0.y * (v0.y - mean) * inv + h0.y;
  y0.z = g0.z * (v0.z - mean) * inv + h0.z;
  y0.w = g0.w * (v0.w - mean) * inv + h0.w;
  y1.x = g1.x * (v1.x - mean) * inv + h1.x;
  y1.y = g1.y * (v1.y - mean) * inv + h1.y;
  y1.z = g1.z * (v1.z - mean) * inv + h1.z;
  y1.w = g1.w * (v1.w - mean) * inv + h1.w;
  float* orow = out + (size_t)ro * 512;
  *(float4*)&orow[lane * 4] = y0;
  *(float4*)&orow[256 + lane * 4] = y1;
}

// ---------------------------------------------------------------------------
extern "C" void kernel_launch(void* const* d_in, const int* in_sizes, int n_in,
                              void* d_out, int out_size, void* d_ws, size_t ws_size,
                              hipStream_t stream) {
  const float* x   = (const float*)d_in[0];
  const float* tse = (const float*)d_in[1];
  const float* sWq = (const float*)d_in[5];  const float* sbq = (const float*)d_in[6];
  const float* sWk = (const float*)d_in[7];  const float* sbk = (const float*)d_in[8];
  const float* sWv = (const float*)d_in[9];  const float* sbv = (const float*)d_in[10];
  const float* sWo = (const float*)d_in[11]; const float* sbo = (const float*)d_in[12];
  const float* tWq = (const float*)d_in[13]; const float* tbq = (const float*)d_in[14];
  const float* tWk = (const float*)d_in[15]; const float* tbk = (const float*)d_in[16];
  const float* tWv = (const float*)d_in[17]; const float* tbv = (const float*)d_in[18];
  const float* tWo = (const float*)d_in[19]; const float* tbo = (const float*)d_in[20];
  const float* ffW1 = (const float*)d_in[21]; const float* ffb1 = (const float*)d_in[22];
  const float* ffW2 = (const float*)d_in[23]; const float* ffb2 = (const float*)d_in[24];
  const float* n1a = (const float*)d_in[25]; const float* n1b = (const float*)d_in[26];
  const float* n2a = (const float*)d_in[27]; const float* n2b = (const float*)d_in[28];
  const float* n3a = (const float*)d_in[29]; const float* n3b = (const float*)d_in[30];

  char* p = (char*)d_ws;
  auto carve = [&](size_t bytes) { void* r = (void*)p; p += (bytes + 255) & ~(size_t)255; return r; };

  unsigned short* sQKVt = (unsigned short*)carve((size_t)3 * 512 * 512 * 2); // sWq^T|sWk^T|sWv^T rows
  unsigned short* sOT   = (unsigned short*)carve((size_t)512 * 512 * 2);
  unsigned short* tQKVt = (unsigned short*)carve((size_t)3 * 512 * 512 * 2);
  unsigned short* tOT   = (unsigned short*)carve((size_t)512 * 512 * 2);
  unsigned short* W1T   = (unsigned short*)carve((size_t)2048 * 512 * 2);
  unsigned short* W2T   = (unsigned short*)carve((size_t)512 * 2048 * 2);
  unsigned short* ktss  = (unsigned short*)carve((size_t)64 * 512 * 2);
  unsigned short* vtss  = (unsigned short*)carve((size_t)64 * 512 * 2);
  unsigned short* ktst  = (unsigned short*)carve((size_t)64 * 512 * 2);
  unsigned short* vtst  = (unsigned short*)carve((size_t)64 * 512 * 2);
  unsigned short* Qb    = (unsigned short*)carve((size_t)M_TOK * 512 * 2);
  float*          Rbuf  = (float*)carve((size_t)M_TOK * 512 * 4);

  unsigned short* Kb = (unsigned short*)d_out;           // K/V bf16 alias d_out while dead as f32
  unsigned short* Vb = Kb + (size_t)M_TOK * 512;
  float* outF = (float*)d_out;

  const float QSCALE = 0.08838834764831845f; // 1/sqrt(128)

  // weight transpose+cast
  {
    dim3 tb(32, 8);
    tcast_k<<<dim3(16, 16), tb, 0, stream>>>(sWq, sQKVt, 512, 512);
    tcast_k<<<dim3(16, 16), tb, 0, stream>>>(sWk, sQKVt + 262144, 512, 512);
    tcast_k<<<dim3(16, 16), tb, 0, stream>>>(sWv, sQKVt + 524288, 512, 512);
    tcast_k<<<dim3(16, 16), tb, 0, stream>>>(sWo, sOT, 512, 512);
    tcast_k<<<dim3(16, 16), tb, 0, stream>>>(tWq, tQKVt, 512, 512);
    tcast_k<<<dim3(16, 16), tb, 0, stream>>>(tWk, tQKVt + 262144, 512, 512);
    tcast_k<<<dim3(16, 16), tb, 0, stream>>>(tWv, tQKVt + 524288, 512, 512);
    tcast_k<<<dim3(16, 16), tb, 0, stream>>>(tWo, tOT, 512, 512);
    tcast_k<<<dim3(64, 16), tb, 0, stream>>>(ffW1, W1T, 512, 2048);
    tcast_k<<<dim3(16, 64), tb, 0, stream>>>(ffW2, W2T, 2048, 512);
  }
  // ts-token K/V projections
  tsproj_k<<<B_DIM, 256, 0, stream>>>(tse, sWk, sbk, ktss);
  tsproj_k<<<B_DIM, 256, 0, stream>>>(tse, sWv, sbv, vtss);
  tsproj_k<<<B_DIM, 256, 0, stream>>>(tse, tWk, tbk, ktst);
  tsproj_k<<<B_DIM, 256, 0, stream>>>(tse, tWv, tbv, vtst);

  const int MT = M_TOK / 128; // 1320

  // ---- spatial attention ----
  gemm_k<true, EPI_QKV><<<dim3(12, MT), 256, 0, stream>>>(
      x, sQKVt, sbq, sbk, sbv, nullptr, nullptr, Qb, Kb, Vb, 512, 512, 512, 512, QSCALE);
  attn_k<22, 23, 24, 256><<<dim3(F_DIM * B_DIM * H_DIM, 1), 256, 0, stream>>>(
      Qb, Kb, Vb, ktss, vtss, Qb);
  gemm_k<false, EPI_RES><<<dim3(4, MT), 256, 0, stream>>>(
      Qb, sOT, sbo, nullptr, nullptr, x, outF, nullptr, nullptr, nullptr, 512, 512, 512, 512, 1.f);
  norm_k<<<M_TOK, 64, 0, stream>>>(outF, Rbuf, n1a, n1b, 1);

  // ---- temporal attention ----
  gemm_k<true, EPI_QKV><<<dim3(12, MT), 256, 0, stream>>>(
      Rbuf, tQKVt, tbq, tbk, tbv, nullptr, nullptr, Qb, Kb, Vb, 512, 512, 512, 512, QSCALE);
  attn_k<40, 121, 124, 512><<<dim3(J_DIM * B_DIM * H_DIM, 3), 512, 0, stream>>>(
      Qb, Kb, Vb, ktst, vtst, Qb);
  gemm_k<false, EPI_RES><<<dim3(4, MT), 256, 0, stream>>>(
      Qb, tOT, tbo, nullptr, nullptr, Rbuf, outF, nullptr, nullptr, nullptr, 512, 512, 512, 512, 1.f);
  norm_k<<<M_TOK, 64, 0, stream>>>(outF, Rbuf, n2a, n2b, 2);

  // ---- feed-forward ----
  if (ws_size >= (size_t)873725952ull) {
    unsigned short* Hb = (unsigned short*)carve((size_t)M_TOK * 1024 * 2);
    for (int c = 0; c < 2; ++c) {
      gemm_k<true, EPI_GELU><<<dim3(8, MT), 256, 0, stream>>>(
          Rbuf, W1T + (size_t)c * 1024 * 512, ffb1 + c * 1024, nullptr, nullptr,
          nullptr, nullptr, Hb, nullptr, nullptr, 512, 512, 1024, 512, 1.f);
      if (c == 0)
        gemm_k<false, EPI_RES><<<dim3(4, MT), 256, 0, stream>>>(
            Hb, W2T + c * 1024, ffb2, nullptr, nullptr, Rbuf, outF,
            nullptr, nullptr, nullptr, 1024, 2048, 512, 1024, 1.f);
      else
        gemm_k<false, EPI_ACC><<<dim3(4, MT), 256, 0, stream>>>(
            Hb, W2T + c * 1024, nullptr, nullptr, nullptr, nullptr, outF,
            nullptr, nullptr, nullptr, 1024, 2048, 512, 1024, 1.f);
    }
  } else {
    // small-ws fallback: chunk hidden through Qb (dead after temporal O-proj)
    for (int c = 0; c < 4; ++c) {
      gemm_k<true, EPI_GELU><<<dim3(4, MT), 256, 0, stream>>>(
          Rbuf, W1T + (size_t)c * 512 * 512, ffb1 + c * 512, nullptr, nullptr,
          nullptr, nullptr, Qb, nullptr, nullptr, 512, 512, 512, 512, 1.f);
      if (c == 0)
        gemm_k<false, EPI_RES><<<dim3(4, MT), 256, 0, stream>>>(
            Qb, W2T + c * 512, ffb2, nullptr, nullptr, Rbuf, outF,
            nullptr, nullptr, nullptr, 512, 2048, 512, 512, 1.f);
      else
        gemm_k<false, EPI_ACC><<<dim3(4, MT), 256, 0, stream>>>(
            Qb, W2T + c * 512, nullptr, nullptr, nullptr, nullptr, outF,
            nullptr, nullptr, nullptr, 512, 2048, 512, 512, 1.f);
    }
  }

  norm_k<<<M_TOK, 64, 0, stream>>>(outF, outF, n3a, n3b, 0);
}

// Round 3
// 4341.531 us; speedup vs baseline: 1.4361x; 1.4361x over previous
//
#include <hip/hip_runtime.h>
#include <hip/hip_bf16.h>
#include <math.h>

// TransformerDecoder2dLayer on MI355X (gfx950).
// Round 3: fix NaN — zero-fill padded key columns of transposed-V LDS tiles
// (uninit LDS * P=0 gave NaN in MFMA PV). Structure unchanged from round 2.
//  tcast x10 (W -> W^T bf16) ; tsproj x4 (ts K/V projections)
//  [spatial]  QKV gemm -> attn_s_k (MFMA) -> O-proj+residual -> norm1(+transpose)
//  [temporal] QKV gemm -> attn_t_k (MFMA) -> O-proj+residual -> norm2(+transpose)
//  [FF]       gelu gemm chunks -> accumulate gemm chunks (+x2 residual) -> norm3

#define F_DIM 120
#define B_DIM 64
#define J_DIM 22
#define H_DIM 4
#define M_TOK (F_DIM * B_DIM * J_DIM) // 168960

#define DEV static __device__ __forceinline__

typedef short bf16x8 __attribute__((ext_vector_type(8)));
typedef float f32x4 __attribute__((ext_vector_type(4)));

struct __align__(8) us4 { unsigned short x, y, z, w; };

DEV unsigned short f2b(float f) {
  unsigned u = __float_as_uint(f);
  u += 0x7fffu + ((u >> 16) & 1u);
  return (unsigned short)(u >> 16);
}
DEV float b2f(unsigned short u) { return __uint_as_float(((unsigned)u) << 16); }

enum { EPI_QKV = 0, EPI_GELU = 1, EPI_RES = 2, EPI_ACC = 3 };

// ---------------------------------------------------------------------------
// Weight transpose + cast: W (K x N f32, row-major) -> WT (N x K bf16)
__global__ __launch_bounds__(256)
void tcast_k(const float* __restrict__ W, unsigned short* __restrict__ WT, int K, int N) {
  __shared__ float t[32][33];
  const int n0 = blockIdx.x * 32, k0 = blockIdx.y * 32;
  const int tx = threadIdx.x, ty = threadIdx.y;
#pragma unroll
  for (int i = 0; i < 4; ++i)
    t[ty + i * 8][tx] = W[(size_t)(k0 + ty + i * 8) * N + n0 + tx];
  __syncthreads();
#pragma unroll
  for (int i = 0; i < 4; ++i)
    WT[(size_t)(n0 + ty + i * 8) * K + k0 + tx] = f2b(t[tx][ty + i * 8]);
}

// ---------------------------------------------------------------------------
// ts-token K/V projection: out[b][n] = sum_k ts[b][k] * W[k][n] + bias[n]  (bf16 out)
__global__ __launch_bounds__(256)
void tsproj_k(const float* __restrict__ ts, const float* __restrict__ W,
              const float* __restrict__ bias, unsigned short* __restrict__ out) {
  __shared__ float tsr[512];
  const int b = blockIdx.x, tid = threadIdx.x;
  for (int i = tid; i < 512; i += 256) tsr[i] = ts[b * 512 + i];
  __syncthreads();
  const int n0 = tid, n1 = tid + 256;
  float a0 = bias[n0], a1 = bias[n1];
  for (int k = 0; k < 512; ++k) {
    const float t = tsr[k];
    a0 += t * W[(size_t)k * 512 + n0];
    a1 += t * W[(size_t)k * 512 + n1];
  }
  out[b * 512 + n0] = f2b(a0);
  out[b * 512 + n1] = f2b(a1);
}

// ---------------------------------------------------------------------------
// Tiled MFMA GEMM: C(M x Ngrid*128) = A(M x nk) @ W(nk x N), W given as WT (N x nk bf16).
// 128x128 tile, BK=32, 4 waves, each wave 64x64 (4x4 of 16x16x32 bf16 MFMA).
template<bool AF32, int EPI>
__global__ __launch_bounds__(256)
void gemm_k(const void* __restrict__ Ap, const unsigned short* __restrict__ Wt,
            const float* __restrict__ b0, const float* __restrict__ b1, const float* __restrict__ b2,
            const float* __restrict__ res, float* __restrict__ outF,
            unsigned short* __restrict__ o0, unsigned short* __restrict__ o1, unsigned short* __restrict__ o2,
            int lda, int ldw, int ldo, int nk, float scale) {
  __shared__ unsigned short As[128][40];
  __shared__ unsigned short Bs[128][40];
  const int tid = threadIdx.x;
  const int nbase = blockIdx.x * 128;   // ntile on x: consecutive blocks share A tile (L2)
  const int mbase = blockIdx.y * 128;
  const int lane = tid & 63;
  const int w = tid >> 6;
  const int wr = (w >> 1) * 64;
  const int wc = (w & 1) * 64;
  const int l15 = lane & 15;
  const int lhi = lane >> 4;

  const float* Af = (const float*)Ap;
  const unsigned short* Ab = (const unsigned short*)Ap;

  float4 ra[4];
  us4 ra16[4];
  us4 rb[4];

  auto loadAB = [&](int kt) {
#pragma unroll
    for (int i = 0; i < 4; ++i) {
      const int g = i * 256 + tid;
      const int r = g >> 3;
      const int c = (g & 7) << 2;
      if constexpr (AF32)
        ra[i] = *(const float4*)(Af + (size_t)(mbase + r) * lda + kt + c);
      else
        ra16[i] = *(const us4*)(Ab + (size_t)(mbase + r) * lda + kt + c);
      rb[i] = *(const us4*)(Wt + (size_t)(nbase + r) * ldw + kt + c);
    }
  };
  auto storeAB = [&]() {
#pragma unroll
    for (int i = 0; i < 4; ++i) {
      const int g = i * 256 + tid;
      const int r = g >> 3;
      const int c = (g & 7) << 2;
      us4 ua;
      if constexpr (AF32) {
        ua.x = f2b(ra[i].x); ua.y = f2b(ra[i].y); ua.z = f2b(ra[i].z); ua.w = f2b(ra[i].w);
      } else ua = ra16[i];
      *(us4*)&As[r][c] = ua;
      *(us4*)&Bs[r][c] = rb[i];
    }
  };

  f32x4 acc[4][4] = {};

  const int KT = nk >> 5;
  loadAB(0);
  storeAB();
  __syncthreads();
  for (int t = 0; t < KT; ++t) {
    if (t + 1 < KT) loadAB((t + 1) << 5);  // prefetch to regs, overlaps MFMA below
    bf16x8 afr[4], bfr[4];
    const int klo = lhi << 3;
#pragma unroll
    for (int i = 0; i < 4; ++i) afr[i] = *(const bf16x8*)&As[wr + i * 16 + l15][klo];
#pragma unroll
    for (int j = 0; j < 4; ++j) bfr[j] = *(const bf16x8*)&Bs[wc + j * 16 + l15][klo];
#pragma unroll
    for (int i = 0; i < 4; ++i)
#pragma unroll
      for (int j = 0; j < 4; ++j)
        acc[i][j] = __builtin_amdgcn_mfma_f32_16x16x32_bf16(afr[i], bfr[j], acc[i][j], 0, 0, 0);
    __syncthreads();
    if (t + 1 < KT) { storeAB(); __syncthreads(); }
  }

#pragma unroll
  for (int i = 0; i < 4; ++i) {
#pragma unroll
    for (int j = 0; j < 4; ++j) {
      const int row0 = mbase + wr + i * 16 + (lhi << 2);
      const int col = nbase + wc + j * 16 + l15;
#pragma unroll
      for (int q = 0; q < 4; ++q) {
        float v = acc[i][j][q];
        const int row = row0 + q;
        if constexpr (EPI == EPI_QKV) {
          const int seg = col >> 9;
          const int cl = col & 511;
          const float* bs = (seg == 0) ? b0 : (seg == 1) ? b1 : b2;
          unsigned short* ob = (seg == 0) ? o0 : (seg == 1) ? o1 : o2;
          const float sc = (seg == 0) ? scale : 1.f;
          v = (v + bs[cl]) * sc;
          ob[(size_t)row * 512 + cl] = f2b(v);
        } else if constexpr (EPI == EPI_GELU) {
          v += b0[col];
          v = 0.5f * v * (1.f + erff(v * 0.70710678118654752f));
          o0[(size_t)row * ldo + col] = f2b(v);
        } else if constexpr (EPI == EPI_RES) {
          const size_t off = (size_t)row * 512 + col;
          v += b0[col] + res[off];
          outF[off] = v;
        } else { // EPI_ACC
          const size_t off = (size_t)row * 512 + col;
          outF[off] = v + outF[off];
        }
      }
    }
  }
}

// ---------------------------------------------------------------------------
// Temporal MFMA attention. Block = (instance, head): 1408*4 blocks, 4 waves.
// Wave w owns S rows [w*32, w*32+32) of the padded 128x128 score tile.
// QK^T: Q rows and K rows read directly from global as A/B fragments.
// Softmax in registers (shfl over 16 lanes). P -> LDS (stride 134 = odd dwords).
// V staged transposed to LDS in two 64-d halves, padded keys ZEROED (NaN fix).
__global__ __launch_bounds__(256)
void attn_t_k(const unsigned short* __restrict__ Qb, const unsigned short* __restrict__ Kb,
              const unsigned short* __restrict__ Vb, const unsigned short* __restrict__ kts,
              const unsigned short* __restrict__ vts, unsigned short* __restrict__ Ob) {
  __shared__ unsigned short Ps[128][134];  // 34.3 KB
  __shared__ unsigned short Vt[64][134];   // 17.2 KB (one d-half, transposed)
  const int tid = threadIdx.x;
  const int inst = blockIdx.x >> 2;
  const int h = blockIdx.x & 3;
  const int b = inst & (B_DIM - 1);
  const size_t rowbase = (size_t)inst * 120;
  const int hoff = h * 128;
  const int lane = tid & 63;
  const int w = tid >> 6;
  const int wr = w * 32;
  const int l15 = lane & 15;
  const int lhi = lane >> 4;

  auto stageV = [&](int half) {
    for (int e = tid; e < 2048; e += 256) {   // 128 key-cols x 16 us4 (zero-pad > 120)
      const int d4 = (e & 15) << 2;
      const int key = e >> 4;
      us4 v;
      if (key <= 120) {
        const unsigned short* src = (key == 0) ? (vts + b * 512) : (Vb + (rowbase + key - 1) * 512);
        v = *(const us4*)(src + hoff + half * 64 + d4);
      } else { v.x = 0; v.y = 0; v.z = 0; v.w = 0; }
      Vt[d4 + 0][key] = v.x; Vt[d4 + 1][key] = v.y; Vt[d4 + 2][key] = v.z; Vt[d4 + 3][key] = v.w;
    }
  };
  stageV(0);  // overlaps with QK^T below (no dependency until first barrier)

  // Q fragments preloaded (wave reads only its own 32 rows)
  bf16x8 qa[2][4];
#pragma unroll
  for (int i = 0; i < 2; ++i) {
    const int row = min(wr + i * 16 + l15, 119);
    const unsigned short* qp = Qb + (rowbase + row) * 512 + hoff;
#pragma unroll
    for (int kt = 0; kt < 4; ++kt)
      qa[i][kt] = *(const bf16x8*)(qp + kt * 32 + lhi * 8);
  }

  f32x4 acc[2][8] = {};
#pragma unroll
  for (int kt = 0; kt < 4; ++kt) {
    const int klo = kt * 32 + lhi * 8;
    bf16x8 kb[8];
#pragma unroll
    for (int j = 0; j < 8; ++j) {
      const int key = min(j * 16 + l15, 120);
      const unsigned short* kp = (key == 0) ? (kts + b * 512) : (Kb + (rowbase + key - 1) * 512);
      kb[j] = *(const bf16x8*)(kp + hoff + klo);
    }
#pragma unroll
    for (int i = 0; i < 2; ++i)
#pragma unroll
      for (int j = 0; j < 8; ++j)
        acc[i][j] = __builtin_amdgcn_mfma_f32_16x16x32_bf16(qa[i][kt], kb[j], acc[i][j], 0, 0, 0);
  }

  // softmax: row = wr + i*16 + lhi*4 + q ; col = j*16 + l15, valid col <= 120
  float rinv[2][4];
#pragma unroll
  for (int i = 0; i < 2; ++i)
#pragma unroll
    for (int q = 0; q < 4; ++q) {
      float m = -1e30f;
#pragma unroll
      for (int j = 0; j < 8; ++j)
        if (j * 16 + l15 <= 120) m = fmaxf(m, acc[i][j][q]);
#pragma unroll
      for (int mk = 1; mk < 16; mk <<= 1) m = fmaxf(m, __shfl_xor(m, mk, 64));
      float s = 0.f;
#pragma unroll
      for (int j = 0; j < 8; ++j) {
        const float e = (j * 16 + l15 <= 120) ? __expf(acc[i][j][q] - m) : 0.f;
        acc[i][j][q] = e; s += e;
      }
#pragma unroll
      for (int mk = 1; mk < 16; mk <<= 1) s += __shfl_xor(s, mk, 64);
      rinv[i][q] = 1.f / s;  // 1/sum deferred to the output store
    }

  // P (unnormalized, <=1) -> LDS bf16
#pragma unroll
  for (int i = 0; i < 2; ++i)
#pragma unroll
    for (int j = 0; j < 8; ++j)
#pragma unroll
      for (int q = 0; q < 4; ++q)
        Ps[wr + i * 16 + lhi * 4 + q][j * 16 + l15] = f2b(acc[i][j][q]);

  __syncthreads();

#pragma unroll
  for (int half = 0; half < 2; ++half) {
    if (half == 1) {
      __syncthreads();
      stageV(1);
      __syncthreads();
    }
    f32x4 oac[2][4] = {};
#pragma unroll
    for (int kt = 0; kt < 4; ++kt) {
      const int klo = kt * 32 + lhi * 8;
      bf16x8 pa[2], vb[4];
#pragma unroll
      for (int i = 0; i < 2; ++i) pa[i] = *(const bf16x8*)&Ps[wr + i * 16 + l15][klo];
#pragma unroll
      for (int jd = 0; jd < 4; ++jd) vb[jd] = *(const bf16x8*)&Vt[jd * 16 + l15][klo];
#pragma unroll
      for (int i = 0; i < 2; ++i)
#pragma unroll
        for (int jd = 0; jd < 4; ++jd)
          oac[i][jd] = __builtin_amdgcn_mfma_f32_16x16x32_bf16(pa[i], vb[jd], oac[i][jd], 0, 0, 0);
    }
#pragma unroll
    for (int i = 0; i < 2; ++i)
#pragma unroll
      for (int q = 0; q < 4; ++q) {
        const int r = wr + i * 16 + lhi * 4 + q;
        if (r < 120) {
          const float sc = rinv[i][q];
#pragma unroll
          for (int jd = 0; jd < 4; ++jd)
            Ob[(rowbase + r) * 512 + hoff + half * 64 + jd * 16 + l15] = f2b(oac[i][jd][q] * sc);
        }
      }
  }
}

// ---------------------------------------------------------------------------
// Spatial MFMA attention. Block = (f,b) instance (7680 blocks), wave = head.
// 22 queries / 23 keys padded to 32. Padded V key-columns ZEROED (NaN fix).
__global__ __launch_bounds__(256)
void attn_s_k(const unsigned short* __restrict__ Qb, const unsigned short* __restrict__ Kb,
              const unsigned short* __restrict__ Vb, const unsigned short* __restrict__ kts,
              const unsigned short* __restrict__ vts, unsigned short* __restrict__ Ob) {
  __shared__ unsigned short Ps[4][32][34];   // 8.7 KB
  __shared__ unsigned short Vt[4][128][34];  // 34.8 KB
  const int tid = threadIdx.x;
  const int inst = blockIdx.x;
  const int b = inst & (B_DIM - 1);
  const size_t rowbase = (size_t)inst * 22;
  const int lane = tid & 63;
  const int h = tid >> 6;  // wave = head
  const int l15 = lane & 15;
  const int lhi = lane >> 4;
  const int hoff = h * 128;

  // stage V transposed for all 4 heads; pad keys 23..31 with zeros
  for (int e = tid; e < 4096; e += 256) {   // 4 heads x 32 key-cols x 32 us4
    const int h2 = e >> 10;
    const int rem = e & 1023;
    const int key = rem >> 5;
    const int d4 = (rem & 31) << 2;
    us4 v;
    if (key <= 22) {
      const unsigned short* src = (key == 0) ? (vts + b * 512) : (Vb + (rowbase + key - 1) * 512);
      v = *(const us4*)(src + h2 * 128 + d4);
    } else { v.x = 0; v.y = 0; v.z = 0; v.w = 0; }
    Vt[h2][d4 + 0][key] = v.x; Vt[h2][d4 + 1][key] = v.y; Vt[h2][d4 + 2][key] = v.z; Vt[h2][d4 + 3][key] = v.w;
  }

  bf16x8 qa[2][4];
#pragma unroll
  for (int i = 0; i < 2; ++i) {
    const int row = min(i * 16 + l15, 21);
    const unsigned short* qp = Qb + (rowbase + row) * 512 + hoff;
#pragma unroll
    for (int kt = 0; kt < 4; ++kt)
      qa[i][kt] = *(const bf16x8*)(qp + kt * 32 + lhi * 8);
  }

  f32x4 acc[2][2] = {};
#pragma unroll
  for (int kt = 0; kt < 4; ++kt) {
    const int klo = kt * 32 + lhi * 8;
    bf16x8 kb[2];
#pragma unroll
    for (int j = 0; j < 2; ++j) {
      const int key = min(j * 16 + l15, 22);
      const unsigned short* kp = (key == 0) ? (kts + b * 512) : (Kb + (rowbase + key - 1) * 512);
      kb[j] = *(const bf16x8*)(kp + hoff + klo);
    }
#pragma unroll
    for (int i = 0; i < 2; ++i)
#pragma unroll
      for (int j = 0; j < 2; ++j)
        acc[i][j] = __builtin_amdgcn_mfma_f32_16x16x32_bf16(qa[i][kt], kb[j], acc[i][j], 0, 0, 0);
  }

  float rinv[2][4];
#pragma unroll
  for (int i = 0; i < 2; ++i)
#pragma unroll
    for (int q = 0; q < 4; ++q) {
      float m = -1e30f;
#pragma unroll
      for (int j = 0; j < 2; ++j)
        if (j * 16 + l15 <= 22) m = fmaxf(m, acc[i][j][q]);
#pragma unroll
      for (int mk = 1; mk < 16; mk <<= 1) m = fmaxf(m, __shfl_xor(m, mk, 64));
      float s = 0.f;
#pragma unroll
      for (int j = 0; j < 2; ++j) {
        const float e = (j * 16 + l15 <= 22) ? __expf(acc[i][j][q] - m) : 0.f;
        acc[i][j][q] = e; s += e;
      }
#pragma unroll
      for (int mk = 1; mk < 16; mk <<= 1) s += __shfl_xor(s, mk, 64);
      rinv[i][q] = 1.f / s;
    }

#pragma unroll
  for (int i = 0; i < 2; ++i)
#pragma unroll
    for (int j = 0; j < 2; ++j)
#pragma unroll
      for (int q = 0; q < 4; ++q)
        Ps[h][i * 16 + lhi * 4 + q][j * 16 + l15] = f2b(acc[i][j][q]);

  __syncthreads();

  f32x4 oac[2][8] = {};
  {
    const int klo = lhi * 8;
    bf16x8 pa[2];
#pragma unroll
    for (int i = 0; i < 2; ++i) pa[i] = *(const bf16x8*)&Ps[h][i * 16 + l15][klo];
#pragma unroll
    for (int jd = 0; jd < 8; ++jd) {
      const bf16x8 vb = *(const bf16x8*)&Vt[h][jd * 16 + l15][klo];
#pragma unroll
      for (int i = 0; i < 2; ++i)
        oac[i][jd] = __builtin_amdgcn_mfma_f32_16x16x32_bf16(pa[i], vb, oac[i][jd], 0, 0, 0);
    }
  }

#pragma unroll
  for (int i = 0; i < 2; ++i)
#pragma unroll
    for (int q = 0; q < 4; ++q) {
      const int r = i * 16 + lhi * 4 + q;
      if (r < 22) {
        const float sc = rinv[i][q];
#pragma unroll
        for (int jd = 0; jd < 8; ++jd)
          Ob[(rowbase + r) * 512 + hoff + jd * 16 + l15] = f2b(oac[i][jd][q] * sc);
      }
    }
}

// ---------------------------------------------------------------------------
// Row norm (torch.std semantics: ddof=1, eps added to sd), fused layout transpose.
// mode 0: identity; mode 1: (F,B,J)->(J,B,F); mode 2: (J,B,F)->(F,B,J)
__global__ __launch_bounds__(64)
void norm_k(const float* __restrict__ in, float* __restrict__ out,
            const float* __restrict__ ga, const float* __restrict__ gb, const int mode) {
  const int r = blockIdx.x;
  const int lane = threadIdx.x;
  const float* row = in + (size_t)r * 512;
  const float4 v0 = *(const float4*)&row[lane * 4];
  const float4 v1 = *(const float4*)&row[256 + lane * 4];
  float s = v0.x + v0.y + v0.z + v0.w + v1.x + v1.y + v1.z + v1.w;
  float ss = v0.x * v0.x + v0.y * v0.y + v0.z * v0.z + v0.w * v0.w
           + v1.x * v1.x + v1.y * v1.y + v1.z * v1.z + v1.w * v1.w;
#pragma unroll
  for (int m = 1; m < 64; m <<= 1) { s += __shfl_xor(s, m, 64); ss += __shfl_xor(ss, m, 64); }
  const float mean = s * (1.f / 512.f);
  const float var = (ss - 512.f * mean * mean) * (1.f / 511.f);
  const float inv = 1.f / (sqrtf(fmaxf(var, 0.f)) + 1e-6f);
  int ro;
  if (mode == 0) ro = r;
  else if (mode == 1) {
    const int f = r / (B_DIM * J_DIM);
    const int bb = (r / J_DIM) % B_DIM;
    const int j = r % J_DIM;
    ro = (j * B_DIM + bb) * F_DIM + f;
  } else {
    const int j = r / (B_DIM * F_DIM);
    const int bb = (r / F_DIM) % B_DIM;
    const int f = r % F_DIM;
    ro = (f * B_DIM + bb) * J_DIM + j;
  }
  const float4 g0 = *(const float4*)&ga[lane * 4];
  const float4 g1 = *(const float4*)&ga[256 + lane * 4];
  const float4 h0 = *(const float4*)&gb[lane * 4];
  const float4 h1 = *(const float4*)&gb[256 + lane * 4];
  float4 y0, y1;
  y0.x = g0.x * (v0.x - mean) * inv + h0.x;
  y0.y = g0.y * (v0.y - mean) * inv + h0.y;
  y0.z = g0.z * (v0.z - mean) * inv + h0.z;
  y0.w = g0.w * (v0.w - mean) * inv + h0.w;
  y1.x = g1.x * (v1.x - mean) * inv + h1.x;
  y1.y = g1.y * (v1.y - mean) * inv + h1.y;
  y1.z = g1.z * (v1.z - mean) * inv + h1.z;
  y1.w = g1.w * (v1.w - mean) * inv + h1.w;
  float* orow = out + (size_t)ro * 512;
  *(float4*)&orow[lane * 4] = y0;
  *(float4*)&orow[256 + lane * 4] = y1;
}

// ---------------------------------------------------------------------------
extern "C" void kernel_launch(void* const* d_in, const int* in_sizes, int n_in,
                              void* d_out, int out_size, void* d_ws, size_t ws_size,
                              hipStream_t stream) {
  const float* x   = (const float*)d_in[0];
  const float* tse = (const float*)d_in[1];
  const float* sWq = (const float*)d_in[5];  const float* sbq = (const float*)d_in[6];
  const float* sWk = (const float*)d_in[7];  const float* sbk = (const float*)d_in[8];
  const float* sWv = (const float*)d_in[9];  const float* sbv = (const float*)d_in[10];
  const float* sWo = (const float*)d_in[11]; const float* sbo = (const float*)d_in[12];
  const float* tWq = (const float*)d_in[13]; const float* tbq = (const float*)d_in[14];
  const float* tWk = (const float*)d_in[15]; const float* tbk = (const float*)d_in[16];
  const float* tWv = (const float*)d_in[17]; const float* tbv = (const float*)d_in[18];
  const float* tWo = (const float*)d_in[19]; const float* tbo = (const float*)d_in[20];
  const float* ffW1 = (const float*)d_in[21]; const float* ffb1 = (const float*)d_in[22];
  const float* ffW2 = (const float*)d_in[23]; const float* ffb2 = (const float*)d_in[24];
  const float* n1a = (const float*)d_in[25]; const float* n1b = (const float*)d_in[26];
  const float* n2a = (const float*)d_in[27]; const float* n2b = (const float*)d_in[28];
  const float* n3a = (const float*)d_in[29]; const float* n3b = (const float*)d_in[30];

  char* p = (char*)d_ws;
  auto carve = [&](size_t bytes) { void* r = (void*)p; p += (bytes + 255) & ~(size_t)255; return r; };

  unsigned short* sQKVt = (unsigned short*)carve((size_t)3 * 512 * 512 * 2); // sWq^T|sWk^T|sWv^T rows
  unsigned short* sOT   = (unsigned short*)carve((size_t)512 * 512 * 2);
  unsigned short* tQKVt = (unsigned short*)carve((size_t)3 * 512 * 512 * 2);
  unsigned short* tOT   = (unsigned short*)carve((size_t)512 * 512 * 2);
  unsigned short* W1T   = (unsigned short*)carve((size_t)2048 * 512 * 2);
  unsigned short* W2T   = (unsigned short*)carve((size_t)512 * 2048 * 2);
  unsigned short* ktss  = (unsigned short*)carve((size_t)64 * 512 * 2);
  unsigned short* vtss  = (unsigned short*)carve((size_t)64 * 512 * 2);
  unsigned short* ktst  = (unsigned short*)carve((size_t)64 * 512 * 2);
  unsigned short* vtst  = (unsigned short*)carve((size_t)64 * 512 * 2);
  unsigned short* Qb    = (unsigned short*)carve((size_t)M_TOK * 512 * 2);
  float*          Rbuf  = (float*)carve((size_t)M_TOK * 512 * 4);

  unsigned short* Kb = (unsigned short*)d_out;           // K/V bf16 alias d_out while dead as f32
  unsigned short* Vb = Kb + (size_t)M_TOK * 512;
  float* outF = (float*)d_out;

  const float QSCALE = 0.08838834764831845f; // 1/sqrt(128)

  // weight transpose+cast
  {
    dim3 tb(32, 8);
    tcast_k<<<dim3(16, 16), tb, 0, stream>>>(sWq, sQKVt, 512, 512);
    tcast_k<<<dim3(16, 16), tb, 0, stream>>>(sWk, sQKVt + 262144, 512, 512);
    tcast_k<<<dim3(16, 16), tb, 0, stream>>>(sWv, sQKVt + 524288, 512, 512);
    tcast_k<<<dim3(16, 16), tb, 0, stream>>>(sWo, sOT, 512, 512);
    tcast_k<<<dim3(16, 16), tb, 0, stream>>>(tWq, tQKVt, 512, 512);
    tcast_k<<<dim3(16, 16), tb, 0, stream>>>(tWk, tQKVt + 262144, 512, 512);
    tcast_k<<<dim3(16, 16), tb, 0, stream>>>(tWv, tQKVt + 524288, 512, 512);
    tcast_k<<<dim3(16, 16), tb, 0, stream>>>(tWo, tOT, 512, 512);
    tcast_k<<<dim3(64, 16), tb, 0, stream>>>(ffW1, W1T, 512, 2048);
    tcast_k<<<dim3(16, 64), tb, 0, stream>>>(ffW2, W2T, 2048, 512);
  }
  // ts-token K/V projections
  tsproj_k<<<B_DIM, 256, 0, stream>>>(tse, sWk, sbk, ktss);
  tsproj_k<<<B_DIM, 256, 0, stream>>>(tse, sWv, sbv, vtss);
  tsproj_k<<<B_DIM, 256, 0, stream>>>(tse, tWk, tbk, ktst);
  tsproj_k<<<B_DIM, 256, 0, stream>>>(tse, tWv, tbv, vtst);

  const int MT = M_TOK / 128; // 1320

  // ---- spatial attention ----
  gemm_k<true, EPI_QKV><<<dim3(12, MT), 256, 0, stream>>>(
      x, sQKVt, sbq, sbk, sbv, nullptr, nullptr, Qb, Kb, Vb, 512, 512, 512, 512, QSCALE);
  attn_s_k<<<dim3(F_DIM * B_DIM), 256, 0, stream>>>(Qb, Kb, Vb, ktss, vtss, Qb);
  gemm_k<false, EPI_RES><<<dim3(4, MT), 256, 0, stream>>>(
      Qb, sOT, sbo, nullptr, nullptr, x, outF, nullptr, nullptr, nullptr, 512, 512, 512, 512, 1.f);
  norm_k<<<M_TOK, 64, 0, stream>>>(outF, Rbuf, n1a, n1b, 1);

  // ---- temporal attention ----
  gemm_k<true, EPI_QKV><<<dim3(12, MT), 256, 0, stream>>>(
      Rbuf, tQKVt, tbq, tbk, tbv, nullptr, nullptr, Qb, Kb, Vb, 512, 512, 512, 512, QSCALE);
  attn_t_k<<<dim3(J_DIM * B_DIM * H_DIM), 256, 0, stream>>>(Qb, Kb, Vb, ktst, vtst, Qb);
  gemm_k<false, EPI_RES><<<dim3(4, MT), 256, 0, stream>>>(
      Qb, tOT, tbo, nullptr, nullptr, Rbuf, outF, nullptr, nullptr, nullptr, 512, 512, 512, 512, 1.f);
  norm_k<<<M_TOK, 64, 0, stream>>>(outF, Rbuf, n2a, n2b, 2);

  // ---- feed-forward ----
  if (ws_size >= (size_t)873725952ull) {
    unsigned short* Hb = (unsigned short*)carve((size_t)M_TOK * 1024 * 2);
    for (int c = 0; c < 2; ++c) {
      gemm_k<true, EPI_GELU><<<dim3(8, MT), 256, 0, stream>>>(
          Rbuf, W1T + (size_t)c * 1024 * 512, ffb1 + c * 1024, nullptr, nullptr,
          nullptr, nullptr, Hb, nullptr, nullptr, 512, 512, 1024, 512, 1.f);
      if (c == 0)
        gemm_k<false, EPI_RES><<<dim3(4, MT), 256, 0, stream>>>(
            Hb, W2T + c * 1024, ffb2, nullptr, nullptr, Rbuf, outF,
            nullptr, nullptr, nullptr, 1024, 2048, 512, 1024, 1.f);
      else
        gemm_k<false, EPI_ACC><<<dim3(4, MT), 256, 0, stream>>>(
            Hb, W2T + c * 1024, nullptr, nullptr, nullptr, nullptr, outF,
            nullptr, nullptr, nullptr, 1024, 2048, 512, 1024, 1.f);
    }
  } else {
    // small-ws fallback: chunk hidden through Qb (dead after temporal O-proj)
    for (int c = 0; c < 4; ++c) {
      gemm_k<true, EPI_GELU><<<dim3(4, MT), 256, 0, stream>>>(
          Rbuf, W1T + (size_t)c * 512 * 512, ffb1 + c * 512, nullptr, nullptr,
          nullptr, nullptr, Qb, nullptr, nullptr, 512, 512, 512, 512, 1.f);
      if (c == 0)
        gemm_k<false, EPI_RES><<<dim3(4, MT), 256, 0, stream>>>(
            Qb, W2T + c * 512, ffb2, nullptr, nullptr, Rbuf, outF,
            nullptr, nullptr, nullptr, 512, 2048, 512, 512, 1.f);
      else
        gemm_k<false, EPI_ACC><<<dim3(4, MT), 256, 0, stream>>>(
            Qb, W2T + c * 512, nullptr, nullptr, nullptr, nullptr, outF,
            nullptr, nullptr, nullptr, 512, 2048, 512, 512, 1.f);
    }
  }

  norm_k<<<M_TOK, 64, 0, stream>>>(outF, outF, n3a, n3b, 0);
}

// Round 4
// 4153.970 us; speedup vs baseline: 1.5009x; 1.0452x over previous
//
#include <hip/hip_runtime.h>
#include <hip/hip_bf16.h>
#include <math.h>

// TransformerDecoder2dLayer on MI355X (gfx950).
// Round 4: XCD-chunked bijective block swizzle in gemm_k (T1). Grid is now 1-D
// with n-tile fastest; each XCD gets contiguous logical blocks = whole y-groups,
// so all n-tiles sharing an A m-tile run on one XCD -> A fetched once (was ~4x).
//  tcast x10 (W -> W^T bf16) ; tsproj x4 (ts K/V projections)
//  [spatial]  QKV gemm -> attn_s_k (MFMA) -> O-proj+residual -> norm1(+transpose)
//  [temporal] QKV gemm -> attn_t_k (MFMA) -> O-proj+residual -> norm2(+transpose)
//  [FF]       gelu gemm chunks -> accumulate gemm chunks (+x2 residual) -> norm3

#define F_DIM 120
#define B_DIM 64
#define J_DIM 22
#define H_DIM 4
#define M_TOK (F_DIM * B_DIM * J_DIM) // 168960

#define DEV static __device__ __forceinline__

typedef short bf16x8 __attribute__((ext_vector_type(8)));
typedef float f32x4 __attribute__((ext_vector_type(4)));

struct __align__(8) us4 { unsigned short x, y, z, w; };

DEV unsigned short f2b(float f) {
  unsigned u = __float_as_uint(f);
  u += 0x7fffu + ((u >> 16) & 1u);
  return (unsigned short)(u >> 16);
}
DEV float b2f(unsigned short u) { return __uint_as_float(((unsigned)u) << 16); }

enum { EPI_QKV = 0, EPI_GELU = 1, EPI_RES = 2, EPI_ACC = 3 };

// ---------------------------------------------------------------------------
// Weight transpose + cast: W (K x N f32, row-major) -> WT (N x K bf16)
__global__ __launch_bounds__(256)
void tcast_k(const float* __restrict__ W, unsigned short* __restrict__ WT, int K, int N) {
  __shared__ float t[32][33];
  const int n0 = blockIdx.x * 32, k0 = blockIdx.y * 32;
  const int tx = threadIdx.x, ty = threadIdx.y;
#pragma unroll
  for (int i = 0; i < 4; ++i)
    t[ty + i * 8][tx] = W[(size_t)(k0 + ty + i * 8) * N + n0 + tx];
  __syncthreads();
#pragma unroll
  for (int i = 0; i < 4; ++i)
    WT[(size_t)(n0 + ty + i * 8) * K + k0 + tx] = f2b(t[tx][ty + i * 8]);
}

// ---------------------------------------------------------------------------
// ts-token K/V projection: out[b][n] = sum_k ts[b][k] * W[k][n] + bias[n]  (bf16 out)
__global__ __launch_bounds__(256)
void tsproj_k(const float* __restrict__ ts, const float* __restrict__ W,
              const float* __restrict__ bias, unsigned short* __restrict__ out) {
  __shared__ float tsr[512];
  const int b = blockIdx.x, tid = threadIdx.x;
  for (int i = tid; i < 512; i += 256) tsr[i] = ts[b * 512 + i];
  __syncthreads();
  const int n0 = tid, n1 = tid + 256;
  float a0 = bias[n0], a1 = bias[n1];
  for (int k = 0; k < 512; ++k) {
    const float t = tsr[k];
    a0 += t * W[(size_t)k * 512 + n0];
    a1 += t * W[(size_t)k * 512 + n1];
  }
  out[b * 512 + n0] = f2b(a0);
  out[b * 512 + n1] = f2b(a1);
}

// ---------------------------------------------------------------------------
// Tiled MFMA GEMM: C(M x nx*128) = A(M x nk) @ W(nk x N), W given as WT (N x nk bf16).
// 128x128 tile, BK=32, 4 waves, each wave 64x64 (4x4 of 16x16x32 bf16 MFMA).
// 1-D grid, n-tile fastest; XCD-chunked swizzle keeps each A m-tile on one XCD.
template<bool AF32, int EPI>
__global__ __launch_bounds__(256)
void gemm_k(const void* __restrict__ Ap, const unsigned short* __restrict__ Wt,
            const float* __restrict__ b0, const float* __restrict__ b1, const float* __restrict__ b2,
            const float* __restrict__ res, float* __restrict__ outF,
            unsigned short* __restrict__ o0, unsigned short* __restrict__ o1, unsigned short* __restrict__ o2,
            int lda, int ldw, int ldo, int nk, int nx, float scale) {
  __shared__ unsigned short As[128][40];
  __shared__ unsigned short Bs[128][40];
  const int tid = threadIdx.x;
  // XCD-chunked bijective swizzle (nwg % 8 == 0 by construction)
  const int chunk = gridDim.x >> 3;
  const int wg = (blockIdx.x & 7) * chunk + (blockIdx.x >> 3);
  const int nbase = (wg % nx) * 128;
  const int mbase = (wg / nx) * 128;
  const int lane = tid & 63;
  const int w = tid >> 6;
  const int wr = (w >> 1) * 64;
  const int wc = (w & 1) * 64;
  const int l15 = lane & 15;
  const int lhi = lane >> 4;

  const float* Af = (const float*)Ap;
  const unsigned short* Ab = (const unsigned short*)Ap;

  float4 ra[4];
  us4 ra16[4];
  us4 rb[4];

  auto loadAB = [&](int kt) {
#pragma unroll
    for (int i = 0; i < 4; ++i) {
      const int g = i * 256 + tid;
      const int r = g >> 3;
      const int c = (g & 7) << 2;
      if constexpr (AF32)
        ra[i] = *(const float4*)(Af + (size_t)(mbase + r) * lda + kt + c);
      else
        ra16[i] = *(const us4*)(Ab + (size_t)(mbase + r) * lda + kt + c);
      rb[i] = *(const us4*)(Wt + (size_t)(nbase + r) * ldw + kt + c);
    }
  };
  auto storeAB = [&]() {
#pragma unroll
    for (int i = 0; i < 4; ++i) {
      const int g = i * 256 + tid;
      const int r = g >> 3;
      const int c = (g & 7) << 2;
      us4 ua;
      if constexpr (AF32) {
        ua.x = f2b(ra[i].x); ua.y = f2b(ra[i].y); ua.z = f2b(ra[i].z); ua.w = f2b(ra[i].w);
      } else ua = ra16[i];
      *(us4*)&As[r][c] = ua;
      *(us4*)&Bs[r][c] = rb[i];
    }
  };

  f32x4 acc[4][4] = {};

  const int KT = nk >> 5;
  loadAB(0);
  storeAB();
  __syncthreads();
  for (int t = 0; t < KT; ++t) {
    if (t + 1 < KT) loadAB((t + 1) << 5);  // prefetch to regs, overlaps MFMA below
    bf16x8 afr[4], bfr[4];
    const int klo = lhi << 3;
#pragma unroll
    for (int i = 0; i < 4; ++i) afr[i] = *(const bf16x8*)&As[wr + i * 16 + l15][klo];
#pragma unroll
    for (int j = 0; j < 4; ++j) bfr[j] = *(const bf16x8*)&Bs[wc + j * 16 + l15][klo];
#pragma unroll
    for (int i = 0; i < 4; ++i)
#pragma unroll
      for (int j = 0; j < 4; ++j)
        acc[i][j] = __builtin_amdgcn_mfma_f32_16x16x32_bf16(afr[i], bfr[j], acc[i][j], 0, 0, 0);
    __syncthreads();
    if (t + 1 < KT) { storeAB(); __syncthreads(); }
  }

#pragma unroll
  for (int i = 0; i < 4; ++i) {
#pragma unroll
    for (int j = 0; j < 4; ++j) {
      const int row0 = mbase + wr + i * 16 + (lhi << 2);
      const int col = nbase + wc + j * 16 + l15;
#pragma unroll
      for (int q = 0; q < 4; ++q) {
        float v = acc[i][j][q];
        const int row = row0 + q;
        if constexpr (EPI == EPI_QKV) {
          const int seg = col >> 9;
          const int cl = col & 511;
          const float* bs = (seg == 0) ? b0 : (seg == 1) ? b1 : b2;
          unsigned short* ob = (seg == 0) ? o0 : (seg == 1) ? o1 : o2;
          const float sc = (seg == 0) ? scale : 1.f;
          v = (v + bs[cl]) * sc;
          ob[(size_t)row * 512 + cl] = f2b(v);
        } else if constexpr (EPI == EPI_GELU) {
          v += b0[col];
          v = 0.5f * v * (1.f + erff(v * 0.70710678118654752f));
          o0[(size_t)row * ldo + col] = f2b(v);
        } else if constexpr (EPI == EPI_RES) {
          const size_t off = (size_t)row * 512 + col;
          v += b0[col] + res[off];
          outF[off] = v;
        } else { // EPI_ACC
          const size_t off = (size_t)row * 512 + col;
          outF[off] = v + outF[off];
        }
      }
    }
  }
}

// ---------------------------------------------------------------------------
// Temporal MFMA attention. Block = (instance, head): 1408*4 blocks, 4 waves.
__global__ __launch_bounds__(256)
void attn_t_k(const unsigned short* __restrict__ Qb, const unsigned short* __restrict__ Kb,
              const unsigned short* __restrict__ Vb, const unsigned short* __restrict__ kts,
              const unsigned short* __restrict__ vts, unsigned short* __restrict__ Ob) {
  __shared__ unsigned short Ps[128][134];  // 34.3 KB
  __shared__ unsigned short Vt[64][134];   // 17.2 KB (one d-half, transposed)
  const int tid = threadIdx.x;
  const int inst = blockIdx.x >> 2;
  const int h = blockIdx.x & 3;
  const int b = inst & (B_DIM - 1);
  const size_t rowbase = (size_t)inst * 120;
  const int hoff = h * 128;
  const int lane = tid & 63;
  const int w = tid >> 6;
  const int wr = w * 32;
  const int l15 = lane & 15;
  const int lhi = lane >> 4;

  auto stageV = [&](int half) {
    for (int e = tid; e < 2048; e += 256) {   // 128 key-cols x 16 us4 (zero-pad > 120)
      const int d4 = (e & 15) << 2;
      const int key = e >> 4;
      us4 v;
      if (key <= 120) {
        const unsigned short* src = (key == 0) ? (vts + b * 512) : (Vb + (rowbase + key - 1) * 512);
        v = *(const us4*)(src + hoff + half * 64 + d4);
      } else { v.x = 0; v.y = 0; v.z = 0; v.w = 0; }
      Vt[d4 + 0][key] = v.x; Vt[d4 + 1][key] = v.y; Vt[d4 + 2][key] = v.z; Vt[d4 + 3][key] = v.w;
    }
  };
  stageV(0);  // overlaps with QK^T below (no dependency until first barrier)

  // Q fragments preloaded (wave reads only its own 32 rows)
  bf16x8 qa[2][4];
#pragma unroll
  for (int i = 0; i < 2; ++i) {
    const int row = min(wr + i * 16 + l15, 119);
    const unsigned short* qp = Qb + (rowbase + row) * 512 + hoff;
#pragma unroll
    for (int kt = 0; kt < 4; ++kt)
      qa[i][kt] = *(const bf16x8*)(qp + kt * 32 + lhi * 8);
  }

  f32x4 acc[2][8] = {};
#pragma unroll
  for (int kt = 0; kt < 4; ++kt) {
    const int klo = kt * 32 + lhi * 8;
    bf16x8 kb[8];
#pragma unroll
    for (int j = 0; j < 8; ++j) {
      const int key = min(j * 16 + l15, 120);
      const unsigned short* kp = (key == 0) ? (kts + b * 512) : (Kb + (rowbase + key - 1) * 512);
      kb[j] = *(const bf16x8*)(kp + hoff + klo);
    }
#pragma unroll
    for (int i = 0; i < 2; ++i)
#pragma unroll
      for (int j = 0; j < 8; ++j)
        acc[i][j] = __builtin_amdgcn_mfma_f32_16x16x32_bf16(qa[i][kt], kb[j], acc[i][j], 0, 0, 0);
  }

  // softmax: row = wr + i*16 + lhi*4 + q ; col = j*16 + l15, valid col <= 120
  float rinv[2][4];
#pragma unroll
  for (int i = 0; i < 2; ++i)
#pragma unroll
    for (int q = 0; q < 4; ++q) {
      float m = -1e30f;
#pragma unroll
      for (int j = 0; j < 8; ++j)
        if (j * 16 + l15 <= 120) m = fmaxf(m, acc[i][j][q]);
#pragma unroll
      for (int mk = 1; mk < 16; mk <<= 1) m = fmaxf(m, __shfl_xor(m, mk, 64));
      float s = 0.f;
#pragma unroll
      for (int j = 0; j < 8; ++j) {
        const float e = (j * 16 + l15 <= 120) ? __expf(acc[i][j][q] - m) : 0.f;
        acc[i][j][q] = e; s += e;
      }
#pragma unroll
      for (int mk = 1; mk < 16; mk <<= 1) s += __shfl_xor(s, mk, 64);
      rinv[i][q] = 1.f / s;  // 1/sum deferred to the output store
    }

  // P (unnormalized, <=1) -> LDS bf16
#pragma unroll
  for (int i = 0; i < 2; ++i)
#pragma unroll
    for (int j = 0; j < 8; ++j)
#pragma unroll
      for (int q = 0; q < 4; ++q)
        Ps[wr + i * 16 + lhi * 4 + q][j * 16 + l15] = f2b(acc[i][j][q]);

  __syncthreads();

#pragma unroll
  for (int half = 0; half < 2; ++half) {
    if (half == 1) {
      __syncthreads();
      stageV(1);
      __syncthreads();
    }
    f32x4 oac[2][4] = {};
#pragma unroll
    for (int kt = 0; kt < 4; ++kt) {
      const int klo = kt * 32 + lhi * 8;
      bf16x8 pa[2], vb[4];
#pragma unroll
      for (int i = 0; i < 2; ++i) pa[i] = *(const bf16x8*)&Ps[wr + i * 16 + l15][klo];
#pragma unroll
      for (int jd = 0; jd < 4; ++jd) vb[jd] = *(const bf16x8*)&Vt[jd * 16 + l15][klo];
#pragma unroll
      for (int i = 0; i < 2; ++i)
#pragma unroll
        for (int jd = 0; jd < 4; ++jd)
          oac[i][jd] = __builtin_amdgcn_mfma_f32_16x16x32_bf16(pa[i], vb[jd], oac[i][jd], 0, 0, 0);
    }
#pragma unroll
    for (int i = 0; i < 2; ++i)
#pragma unroll
      for (int q = 0; q < 4; ++q) {
        const int r = wr + i * 16 + lhi * 4 + q;
        if (r < 120) {
          const float sc = rinv[i][q];
#pragma unroll
          for (int jd = 0; jd < 4; ++jd)
            Ob[(rowbase + r) * 512 + hoff + half * 64 + jd * 16 + l15] = f2b(oac[i][jd][q] * sc);
        }
      }
  }
}

// ---------------------------------------------------------------------------
// Spatial MFMA attention. Block = (f,b) instance (7680 blocks), wave = head.
__global__ __launch_bounds__(256)
void attn_s_k(const unsigned short* __restrict__ Qb, const unsigned short* __restrict__ Kb,
              const unsigned short* __restrict__ Vb, const unsigned short* __restrict__ kts,
              const unsigned short* __restrict__ vts, unsigned short* __restrict__ Ob) {
  __shared__ unsigned short Ps[4][32][34];   // 8.7 KB
  __shared__ unsigned short Vt[4][128][34];  // 34.8 KB
  const int tid = threadIdx.x;
  const int inst = blockIdx.x;
  const int b = inst & (B_DIM - 1);
  const size_t rowbase = (size_t)inst * 22;
  const int lane = tid & 63;
  const int h = tid >> 6;  // wave = head
  const int l15 = lane & 15;
  const int lhi = lane >> 4;
  const int hoff = h * 128;

  // stage V transposed for all 4 heads; pad keys 23..31 with zeros
  for (int e = tid; e < 4096; e += 256) {   // 4 heads x 32 key-cols x 32 us4
    const int h2 = e >> 10;
    const int rem = e & 1023;
    const int key = rem >> 5;
    const int d4 = (rem & 31) << 2;
    us4 v;
    if (key <= 22) {
      const unsigned short* src = (key == 0) ? (vts + b * 512) : (Vb + (rowbase + key - 1) * 512);
      v = *(const us4*)(src + h2 * 128 + d4);
    } else { v.x = 0; v.y = 0; v.z = 0; v.w = 0; }
    Vt[h2][d4 + 0][key] = v.x; Vt[h2][d4 + 1][key] = v.y; Vt[h2][d4 + 2][key] = v.z; Vt[h2][d4 + 3][key] = v.w;
  }

  bf16x8 qa[2][4];
#pragma unroll
  for (int i = 0; i < 2; ++i) {
    const int row = min(i * 16 + l15, 21);
    const unsigned short* qp = Qb + (rowbase + row) * 512 + hoff;
#pragma unroll
    for (int kt = 0; kt < 4; ++kt)
      qa[i][kt] = *(const bf16x8*)(qp + kt * 32 + lhi * 8);
  }

  f32x4 acc[2][2] = {};
#pragma unroll
  for (int kt = 0; kt < 4; ++kt) {
    const int klo = kt * 32 + lhi * 8;
    bf16x8 kb[2];
#pragma unroll
    for (int j = 0; j < 2; ++j) {
      const int key = min(j * 16 + l15, 22);
      const unsigned short* kp = (key == 0) ? (kts + b * 512) : (Kb + (rowbase + key - 1) * 512);
      kb[j] = *(const bf16x8*)(kp + hoff + klo);
    }
#pragma unroll
    for (int i = 0; i < 2; ++i)
#pragma unroll
      for (int j = 0; j < 2; ++j)
        acc[i][j] = __builtin_amdgcn_mfma_f32_16x16x32_bf16(qa[i][kt], kb[j], acc[i][j], 0, 0, 0);
  }

  float rinv[2][4];
#pragma unroll
  for (int i = 0; i < 2; ++i)
#pragma unroll
    for (int q = 0; q < 4; ++q) {
      float m = -1e30f;
#pragma unroll
      for (int j = 0; j < 2; ++j)
        if (j * 16 + l15 <= 22) m = fmaxf(m, acc[i][j][q]);
#pragma unroll
      for (int mk = 1; mk < 16; mk <<= 1) m = fmaxf(m, __shfl_xor(m, mk, 64));
      float s = 0.f;
#pragma unroll
      for (int j = 0; j < 2; ++j) {
        const float e = (j * 16 + l15 <= 22) ? __expf(acc[i][j][q] - m) : 0.f;
        acc[i][j][q] = e; s += e;
      }
#pragma unroll
      for (int mk = 1; mk < 16; mk <<= 1) s += __shfl_xor(s, mk, 64);
      rinv[i][q] = 1.f / s;
    }

#pragma unroll
  for (int i = 0; i < 2; ++i)
#pragma unroll
    for (int j = 0; j < 2; ++j)
#pragma unroll
      for (int q = 0; q < 4; ++q)
        Ps[h][i * 16 + lhi * 4 + q][j * 16 + l15] = f2b(acc[i][j][q]);

  __syncthreads();

  f32x4 oac[2][8] = {};
  {
    const int klo = lhi * 8;
    bf16x8 pa[2];
#pragma unroll
    for (int i = 0; i < 2; ++i) pa[i] = *(const bf16x8*)&Ps[h][i * 16 + l15][klo];
#pragma unroll
    for (int jd = 0; jd < 8; ++jd) {
      const bf16x8 vb = *(const bf16x8*)&Vt[h][jd * 16 + l15][klo];
#pragma unroll
      for (int i = 0; i < 2; ++i)
        oac[i][jd] = __builtin_amdgcn_mfma_f32_16x16x32_bf16(pa[i], vb, oac[i][jd], 0, 0, 0);
    }
  }

#pragma unroll
  for (int i = 0; i < 2; ++i)
#pragma unroll
    for (int q = 0; q < 4; ++q) {
      const int r = i * 16 + lhi * 4 + q;
      if (r < 22) {
        const float sc = rinv[i][q];
#pragma unroll
        for (int jd = 0; jd < 8; ++jd)
          Ob[(rowbase + r) * 512 + hoff + jd * 16 + l15] = f2b(oac[i][jd][q] * sc);
      }
    }
}

// ---------------------------------------------------------------------------
// Row norm (torch.std semantics: ddof=1, eps added to sd), fused layout transpose.
// mode 0: identity; mode 1: (F,B,J)->(J,B,F); mode 2: (J,B,F)->(F,B,J)
__global__ __launch_bounds__(64)
void norm_k(const float* __restrict__ in, float* __restrict__ out,
            const float* __restrict__ ga, const float* __restrict__ gb, const int mode) {
  const int r = blockIdx.x;
  const int lane = threadIdx.x;
  const float* row = in + (size_t)r * 512;
  const float4 v0 = *(const float4*)&row[lane * 4];
  const float4 v1 = *(const float4*)&row[256 + lane * 4];
  float s = v0.x + v0.y + v0.z + v0.w + v1.x + v1.y + v1.z + v1.w;
  float ss = v0.x * v0.x + v0.y * v0.y + v0.z * v0.z + v0.w * v0.w
           + v1.x * v1.x + v1.y * v1.y + v1.z * v1.z + v1.w * v1.w;
#pragma unroll
  for (int m = 1; m < 64; m <<= 1) { s += __shfl_xor(s, m, 64); ss += __shfl_xor(ss, m, 64); }
  const float mean = s * (1.f / 512.f);
  const float var = (ss - 512.f * mean * mean) * (1.f / 511.f);
  const float inv = 1.f / (sqrtf(fmaxf(var, 0.f)) + 1e-6f);
  int ro;
  if (mode == 0) ro = r;
  else if (mode == 1) {
    const int f = r / (B_DIM * J_DIM);
    const int bb = (r / J_DIM) % B_DIM;
    const int j = r % J_DIM;
    ro = (j * B_DIM + bb) * F_DIM + f;
  } else {
    const int j = r / (B_DIM * F_DIM);
    const int bb = (r / F_DIM) % B_DIM;
    const int f = r % F_DIM;
    ro = (f * B_DIM + bb) * J_DIM + j;
  }
  const float4 g0 = *(const float4*)&ga[lane * 4];
  const float4 g1 = *(const float4*)&ga[256 + lane * 4];
  const float4 h0 = *(const float4*)&gb[lane * 4];
  const float4 h1 = *(const float4*)&gb[256 + lane * 4];
  float4 y0, y1;
  y0.x = g0.x * (v0.x - mean) * inv + h0.x;
  y0.y = g0.y * (v0.y - mean) * inv + h0.y;
  y0.z = g0.z * (v0.z - mean) * inv + h0.z;
  y0.w = g0.w * (v0.w - mean) * inv + h0.w;
  y1.x = g1.x * (v1.x - mean) * inv + h1.x;
  y1.y = g1.y * (v1.y - mean) * inv + h1.y;
  y1.z = g1.z * (v1.z - mean) * inv + h1.z;
  y1.w = g1.w * (v1.w - mean) * inv + h1.w;
  float* orow = out + (size_t)ro * 512;
  *(float4*)&orow[lane * 4] = y0;
  *(float4*)&orow[256 + lane * 4] = y1;
}

// ---------------------------------------------------------------------------
extern "C" void kernel_launch(void* const* d_in, const int* in_sizes, int n_in,
                              void* d_out, int out_size, void* d_ws, size_t ws_size,
                              hipStream_t stream) {
  const float* x   = (const float*)d_in[0];
  const float* tse = (const float*)d_in[1];
  const float* sWq = (const float*)d_in[5];  const float* sbq = (const float*)d_in[6];
  const float* sWk = (const float*)d_in[7];  const float* sbk = (const float*)d_in[8];
  const float* sWv = (const float*)d_in[9];  const float* sbv = (const float*)d_in[10];
  const float* sWo = (const float*)d_in[11]; const float* sbo = (const float*)d_in[12];
  const float* tWq = (const float*)d_in[13]; const float* tbq = (const float*)d_in[14];
  const float* tWk = (const float*)d_in[15]; const float* tbk = (const float*)d_in[16];
  const float* tWv = (const float*)d_in[17]; const float* tbv = (const float*)d_in[18];
  const float* tWo = (const float*)d_in[19]; const float* tbo = (const float*)d_in[20];
  const float* ffW1 = (const float*)d_in[21]; const float* ffb1 = (const float*)d_in[22];
  const float* ffW2 = (const float*)d_in[23]; const float* ffb2 = (const float*)d_in[24];
  const float* n1a = (const float*)d_in[25]; const float* n1b = (const float*)d_in[26];
  const float* n2a = (const float*)d_in[27]; const float* n2b = (const float*)d_in[28];
  const float* n3a = (const float*)d_in[29]; const float* n3b = (const float*)d_in[30];

  char* p = (char*)d_ws;
  auto carve = [&](size_t bytes) { void* r = (void*)p; p += (bytes + 255) & ~(size_t)255; return r; };

  unsigned short* sQKVt = (unsigned short*)carve((size_t)3 * 512 * 512 * 2); // sWq^T|sWk^T|sWv^T rows
  unsigned short* sOT   = (unsigned short*)carve((size_t)512 * 512 * 2);
  unsigned short* tQKVt = (unsigned short*)carve((size_t)3 * 512 * 512 * 2);
  unsigned short* tOT   = (unsigned short*)carve((size_t)512 * 512 * 2);
  unsigned short* W1T   = (unsigned short*)carve((size_t)2048 * 512 * 2);
  unsigned short* W2T   = (unsigned short*)carve((size_t)512 * 2048 * 2);
  unsigned short* ktss  = (unsigned short*)carve((size_t)64 * 512 * 2);
  unsigned short* vtss  = (unsigned short*)carve((size_t)64 * 512 * 2);
  unsigned short* ktst  = (unsigned short*)carve((size_t)64 * 512 * 2);
  unsigned short* vtst  = (unsigned short*)carve((size_t)64 * 512 * 2);
  unsigned short* Qb    = (unsigned short*)carve((size_t)M_TOK * 512 * 2);
  float*          Rbuf  = (float*)carve((size_t)M_TOK * 512 * 4);

  unsigned short* Kb = (unsigned short*)d_out;           // K/V bf16 alias d_out while dead as f32
  unsigned short* Vb = Kb + (size_t)M_TOK * 512;
  float* outF = (float*)d_out;

  const float QSCALE = 0.08838834764831845f; // 1/sqrt(128)

  // weight transpose+cast
  {
    dim3 tb(32, 8);
    tcast_k<<<dim3(16, 16), tb, 0, stream>>>(sWq, sQKVt, 512, 512);
    tcast_k<<<dim3(16, 16), tb, 0, stream>>>(sWk, sQKVt + 262144, 512, 512);
    tcast_k<<<dim3(16, 16), tb, 0, stream>>>(sWv, sQKVt + 524288, 512, 512);
    tcast_k<<<dim3(16, 16), tb, 0, stream>>>(sWo, sOT, 512, 512);
    tcast_k<<<dim3(16, 16), tb, 0, stream>>>(tWq, tQKVt, 512, 512);
    tcast_k<<<dim3(16, 16), tb, 0, stream>>>(tWk, tQKVt + 262144, 512, 512);
    tcast_k<<<dim3(16, 16), tb, 0, stream>>>(tWv, tQKVt + 524288, 512, 512);
    tcast_k<<<dim3(16, 16), tb, 0, stream>>>(tWo, tOT, 512, 512);
    tcast_k<<<dim3(64, 16), tb, 0, stream>>>(ffW1, W1T, 512, 2048);
    tcast_k<<<dim3(16, 64), tb, 0, stream>>>(ffW2, W2T, 2048, 512);
  }
  // ts-token K/V projections
  tsproj_k<<<B_DIM, 256, 0, stream>>>(tse, sWk, sbk, ktss);
  tsproj_k<<<B_DIM, 256, 0, stream>>>(tse, sWv, sbv, vtss);
  tsproj_k<<<B_DIM, 256, 0, stream>>>(tse, tWk, tbk, ktst);
  tsproj_k<<<B_DIM, 256, 0, stream>>>(tse, tWv, tbv, vtst);

  const int MT = M_TOK / 128; // 1320 (= 8*165, all grids below are %8==0)

  // ---- spatial attention ----
  gemm_k<true, EPI_QKV><<<12 * MT, 256, 0, stream>>>(
      x, sQKVt, sbq, sbk, sbv, nullptr, nullptr, Qb, Kb, Vb, 512, 512, 512, 512, 12, QSCALE);
  attn_s_k<<<dim3(F_DIM * B_DIM), 256, 0, stream>>>(Qb, Kb, Vb, ktss, vtss, Qb);
  gemm_k<false, EPI_RES><<<4 * MT, 256, 0, stream>>>(
      Qb, sOT, sbo, nullptr, nullptr, x, outF, nullptr, nullptr, nullptr, 512, 512, 512, 512, 4, 1.f);
  norm_k<<<M_TOK, 64, 0, stream>>>(outF, Rbuf, n1a, n1b, 1);

  // ---- temporal attention ----
  gemm_k<true, EPI_QKV><<<12 * MT, 256, 0, stream>>>(
      Rbuf, tQKVt, tbq, tbk, tbv, nullptr, nullptr, Qb, Kb, Vb, 512, 512, 512, 512, 12, QSCALE);
  attn_t_k<<<dim3(J_DIM * B_DIM * H_DIM), 256, 0, stream>>>(Qb, Kb, Vb, ktst, vtst, Qb);
  gemm_k<false, EPI_RES><<<4 * MT, 256, 0, stream>>>(
      Qb, tOT, tbo, nullptr, nullptr, Rbuf, outF, nullptr, nullptr, nullptr, 512, 512, 512, 512, 4, 1.f);
  norm_k<<<M_TOK, 64, 0, stream>>>(outF, Rbuf, n2a, n2b, 2);

  // ---- feed-forward ----
  if (ws_size >= (size_t)873725952ull) {
    unsigned short* Hb = (unsigned short*)carve((size_t)M_TOK * 1024 * 2);
    for (int c = 0; c < 2; ++c) {
      gemm_k<true, EPI_GELU><<<8 * MT, 256, 0, stream>>>(
          Rbuf, W1T + (size_t)c * 1024 * 512, ffb1 + c * 1024, nullptr, nullptr,
          nullptr, nullptr, Hb, nullptr, nullptr, 512, 512, 1024, 512, 8, 1.f);
      if (c == 0)
        gemm_k<false, EPI_RES><<<4 * MT, 256, 0, stream>>>(
            Hb, W2T + c * 1024, ffb2, nullptr, nullptr, Rbuf, outF,
            nullptr, nullptr, nullptr, 1024, 2048, 512, 1024, 4, 1.f);
      else
        gemm_k<false, EPI_ACC><<<4 * MT, 256, 0, stream>>>(
            Hb, W2T + c * 1024, nullptr, nullptr, nullptr, nullptr, outF,
            nullptr, nullptr, nullptr, 1024, 2048, 512, 1024, 4, 1.f);
    }
  } else {
    // small-ws fallback: chunk hidden through Qb (dead after temporal O-proj)
    for (int c = 0; c < 4; ++c) {
      gemm_k<true, EPI_GELU><<<4 * MT, 256, 0, stream>>>(
          Rbuf, W1T + (size_t)c * 512 * 512, ffb1 + c * 512, nullptr, nullptr,
          nullptr, nullptr, Qb, nullptr, nullptr, 512, 512, 512, 512, 4, 1.f);
      if (c == 0)
        gemm_k<false, EPI_RES><<<4 * MT, 256, 0, stream>>>(
            Qb, W2T + c * 512, ffb2, nullptr, nullptr, Rbuf, outF,
            nullptr, nullptr, nullptr, 512, 2048, 512, 512, 4, 1.f);
      else
        gemm_k<false, EPI_ACC><<<4 * MT, 256, 0, stream>>>(
            Qb, W2T + c * 512, nullptr, nullptr, nullptr, nullptr, outF,
            nullptr, nullptr, nullptr, 512, 2048, 512, 512, 4, 1.f);
    }
  }

  norm_k<<<M_TOK, 64, 0, stream>>>(outF, outF, n3a, n3b, 0);
}

// Round 5
// 3772.044 us; speedup vs baseline: 1.6529x; 1.1013x over previous
//
#include <hip/hip_runtime.h>
#include <hip/hip_bf16.h>
#include <math.h>

// TransformerDecoder2dLayer on MI355X (gfx950).
// Round 5: m97-structure GEMM — global_load_lds (16B) direct staging, double-
// buffered linear LDS, bf16 A everywhere (cast_k for x, norm_k dual-output).
// XCD-chunked swizzle retained. attn kernels unchanged (MFMA, round 3).

#define F_DIM 120
#define B_DIM 64
#define J_DIM 22
#define H_DIM 4
#define M_TOK (F_DIM * B_DIM * J_DIM) // 168960

#define DEV static __device__ __forceinline__

typedef short bf16x8 __attribute__((ext_vector_type(8)));
typedef short us8 __attribute__((ext_vector_type(8)));
typedef float f32x4 __attribute__((ext_vector_type(4)));

struct __align__(8) us4 { unsigned short x, y, z, w; };

DEV unsigned short f2b(float f) {
  unsigned u = __float_as_uint(f);
  u += 0x7fffu + ((u >> 16) & 1u);
  return (unsigned short)(u >> 16);
}
DEV float b2f(unsigned short u) { return __uint_as_float(((unsigned)u) << 16); }

#define GLOAD16(g, l)                                                          \
  __builtin_amdgcn_global_load_lds(                                            \
      (const __attribute__((address_space(1))) void*)(g),                      \
      (__attribute__((address_space(3))) void*)(l), 16, 0, 0)

enum { EPI_QKV = 0, EPI_GELU = 1, EPI_RES = 2, EPI_ACC = 3 };

// ---------------------------------------------------------------------------
// f32 -> bf16 cast, 8 elems/thread, grid-stride.
__global__ __launch_bounds__(256)
void cast_k(const float* __restrict__ in, unsigned short* __restrict__ out, int n8) {
  for (int i = blockIdx.x * 256 + threadIdx.x; i < n8; i += gridDim.x * 256) {
    const float4 a = ((const float4*)in)[i * 2];
    const float4 b = ((const float4*)in)[i * 2 + 1];
    us8 v;
    v[0] = f2b(a.x); v[1] = f2b(a.y); v[2] = f2b(a.z); v[3] = f2b(a.w);
    v[4] = f2b(b.x); v[5] = f2b(b.y); v[6] = f2b(b.z); v[7] = f2b(b.w);
    *(us8*)&out[i * 8] = v;
  }
}

// ---------------------------------------------------------------------------
// Weight transpose + cast: W (K x N f32, row-major) -> WT (N x K bf16)
__global__ __launch_bounds__(256)
void tcast_k(const float* __restrict__ W, unsigned short* __restrict__ WT, int K, int N) {
  __shared__ float t[32][33];
  const int n0 = blockIdx.x * 32, k0 = blockIdx.y * 32;
  const int tx = threadIdx.x, ty = threadIdx.y;
#pragma unroll
  for (int i = 0; i < 4; ++i)
    t[ty + i * 8][tx] = W[(size_t)(k0 + ty + i * 8) * N + n0 + tx];
  __syncthreads();
#pragma unroll
  for (int i = 0; i < 4; ++i)
    WT[(size_t)(n0 + ty + i * 8) * K + k0 + tx] = f2b(t[tx][ty + i * 8]);
}

// ---------------------------------------------------------------------------
// ts-token K/V projection: out[b][n] = sum_k ts[b][k] * W[k][n] + bias[n]  (bf16 out)
__global__ __launch_bounds__(256)
void tsproj_k(const float* __restrict__ ts, const float* __restrict__ W,
              const float* __restrict__ bias, unsigned short* __restrict__ out) {
  __shared__ float tsr[512];
  const int b = blockIdx.x, tid = threadIdx.x;
  for (int i = tid; i < 512; i += 256) tsr[i] = ts[b * 512 + i];
  __syncthreads();
  const int n0 = tid, n1 = tid + 256;
  float a0 = bias[n0], a1 = bias[n1];
  for (int k = 0; k < 512; ++k) {
    const float t = tsr[k];
    a0 += t * W[(size_t)k * 512 + n0];
    a1 += t * W[(size_t)k * 512 + n1];
  }
  out[b * 512 + n0] = f2b(a0);
  out[b * 512 + n1] = f2b(a1);
}

// ---------------------------------------------------------------------------
// GEMM epilogue shared by both kernel variants.
template<int EPI>
DEV void gemm_epilogue(f32x4 (&acc)[4][4], int mbase, int nbase, int wr, int wc,
                       int l15, int lhi, const float* b0, const float* res,
                       float* outF, unsigned short* o0, unsigned short* o1,
                       unsigned short* o2, const float* b1, const float* b2,
                       int ldo, float scale) {
#pragma unroll
  for (int i = 0; i < 4; ++i) {
#pragma unroll
    for (int j = 0; j < 4; ++j) {
      const int row0 = mbase + wr + i * 16 + (lhi << 2);
      const int col = nbase + wc + j * 16 + l15;
#pragma unroll
      for (int q = 0; q < 4; ++q) {
        float v = acc[i][j][q];
        const int row = row0 + q;
        if constexpr (EPI == EPI_QKV) {
          const int seg = col >> 9;
          const int cl = col & 511;
          const float* bs = (seg == 0) ? b0 : (seg == 1) ? b1 : b2;
          unsigned short* ob = (seg == 0) ? o0 : (seg == 1) ? o1 : o2;
          const float sc = (seg == 0) ? scale : 1.f;
          v = (v + bs[cl]) * sc;
          ob[(size_t)row * 512 + cl] = f2b(v);
        } else if constexpr (EPI == EPI_GELU) {
          v += b0[col];
          v = 0.5f * v * (1.f + erff(v * 0.70710678118654752f));
          o0[(size_t)row * ldo + col] = f2b(v);
        } else if constexpr (EPI == EPI_RES) {
          const size_t off = (size_t)row * 512 + col;
          v += b0[col] + res[off];
          outF[off] = v;
        } else { // EPI_ACC
          const size_t off = (size_t)row * 512 + col;
          outF[off] = v + outF[off];
        }
      }
    }
  }
}

// ---------------------------------------------------------------------------
// m97-structure GEMM: C(M x nx*128) = A(M x nk) @ W(nk x N); A bf16, W as WT bf16.
// 128x128 tile, BK=32, 4 waves (4x4 16x16x32 MFMA each). global_load_lds 16B
// staging into double-buffered linear LDS [128][32]; vmcnt(0)+barrier per step.
template<int EPI>
__global__ __launch_bounds__(256)
void gemm_k(const unsigned short* __restrict__ Ab, const unsigned short* __restrict__ Wt,
            const float* __restrict__ b0, const float* __restrict__ b1, const float* __restrict__ b2,
            const float* __restrict__ res, float* __restrict__ outF,
            unsigned short* __restrict__ o0, unsigned short* __restrict__ o1, unsigned short* __restrict__ o2,
            int lda, int ldw, int ldo, int nk, int nx, float scale) {
  __shared__ unsigned short As[2][4096];
  __shared__ unsigned short Bs[2][4096];
  const int tid = threadIdx.x;
  const int chunkg = gridDim.x >> 3;     // XCD-chunked bijective swizzle (nwg%8==0)
  const int wg = (blockIdx.x & 7) * chunkg + (blockIdx.x >> 3);
  const int nbase = (wg % nx) * 128;
  const int mbase = (wg / nx) * 128;
  const int lane = tid & 63;
  const int w = tid >> 6;
  const int wr = (w >> 1) * 64;
  const int wc = (w & 1) * 64;
  const int l15 = lane & 15;
  const int lhi = lane >> 4;

  // Staging geometry: wave w owns chunks {2w, 2w+1} of A and B. One
  // global_load_lds = 64 lanes x 16B = 1KB = 16 rows of [32 bf16].
  // lane l -> row 16c + (l>>2), k-col (l&3)*8; LDS dest linear (HW: base+lane*16).
  const int crow = lane >> 2;
  const int ccol = (lane & 3) << 3;
  const unsigned short* gA0 = Ab + (size_t)(mbase + 32 * w + crow) * lda + ccol;
  const unsigned short* gA1 = gA0 + (size_t)16 * lda;
  const unsigned short* gB0 = Wt + (size_t)(nbase + 32 * w + crow) * ldw + ccol;
  const unsigned short* gB1 = gB0 + (size_t)16 * ldw;

  auto stage = [&](int bb, int kt) {
    GLOAD16(gA0 + kt, &As[bb][(2 * w) * 512]);
    GLOAD16(gA1 + kt, &As[bb][(2 * w + 1) * 512]);
    GLOAD16(gB0 + kt, &Bs[bb][(2 * w) * 512]);
    GLOAD16(gB1 + kt, &Bs[bb][(2 * w + 1) * 512]);
  };

  f32x4 acc[4][4] = {};
  const int KT = nk >> 5;

  stage(0, 0);
  asm volatile("s_waitcnt vmcnt(0)" ::: "memory");
  __syncthreads();
  for (int t = 0; t < KT; ++t) {
    const int bb = t & 1;
    const int klo = lhi << 3;
    bf16x8 afr[4], bfr[4];
#pragma unroll
    for (int i = 0; i < 4; ++i) afr[i] = *(const bf16x8*)&As[bb][(wr + i * 16 + l15) * 32 + klo];
#pragma unroll
    for (int j = 0; j < 4; ++j) bfr[j] = *(const bf16x8*)&Bs[bb][(wc + j * 16 + l15) * 32 + klo];
    if (t + 1 < KT) stage(bb ^ 1, (t + 1) << 5);   // prefetch into other buffer
#pragma unroll
    for (int i = 0; i < 4; ++i)
#pragma unroll
      for (int j = 0; j < 4; ++j)
        acc[i][j] = __builtin_amdgcn_mfma_f32_16x16x32_bf16(afr[i], bfr[j], acc[i][j], 0, 0, 0);
    asm volatile("s_waitcnt vmcnt(0)" ::: "memory");
    __syncthreads();
  }

  gemm_epilogue<EPI>(acc, mbase, nbase, wr, wc, l15, lhi, b0, res, outF, o0, o1, o2, b1, b2, ldo, scale);
}

// ---------------------------------------------------------------------------
// Legacy reg-staging GEMM for f32 A (small-ws fallback only).
template<int EPI>
__global__ __launch_bounds__(256)
void gemmf_k(const float* __restrict__ Af, const unsigned short* __restrict__ Wt,
             const float* __restrict__ b0, const float* __restrict__ b1, const float* __restrict__ b2,
             const float* __restrict__ res, float* __restrict__ outF,
             unsigned short* __restrict__ o0, unsigned short* __restrict__ o1, unsigned short* __restrict__ o2,
             int lda, int ldw, int ldo, int nk, int nx, float scale) {
  __shared__ unsigned short As[128][40];
  __shared__ unsigned short Bs[128][40];
  const int tid = threadIdx.x;
  const int chunkg = gridDim.x >> 3;
  const int wg = (blockIdx.x & 7) * chunkg + (blockIdx.x >> 3);
  const int nbase = (wg % nx) * 128;
  const int mbase = (wg / nx) * 128;
  const int lane = tid & 63;
  const int w = tid >> 6;
  const int wr = (w >> 1) * 64;
  const int wc = (w & 1) * 64;
  const int l15 = lane & 15;
  const int lhi = lane >> 4;

  float4 ra[4];
  us4 rb[4];
  auto loadAB = [&](int kt) {
#pragma unroll
    for (int i = 0; i < 4; ++i) {
      const int g = i * 256 + tid;
      const int r = g >> 3;
      const int c = (g & 7) << 2;
      ra[i] = *(const float4*)(Af + (size_t)(mbase + r) * lda + kt + c);
      rb[i] = *(const us4*)(Wt + (size_t)(nbase + r) * ldw + kt + c);
    }
  };
  auto storeAB = [&]() {
#pragma unroll
    for (int i = 0; i < 4; ++i) {
      const int g = i * 256 + tid;
      const int r = g >> 3;
      const int c = (g & 7) << 2;
      us4 ua;
      ua.x = f2b(ra[i].x); ua.y = f2b(ra[i].y); ua.z = f2b(ra[i].z); ua.w = f2b(ra[i].w);
      *(us4*)&As[r][c] = ua;
      *(us4*)&Bs[r][c] = rb[i];
    }
  };

  f32x4 acc[4][4] = {};
  const int KT = nk >> 5;
  loadAB(0);
  storeAB();
  __syncthreads();
  for (int t = 0; t < KT; ++t) {
    if (t + 1 < KT) loadAB((t + 1) << 5);
    bf16x8 afr[4], bfr[4];
    const int klo = lhi << 3;
#pragma unroll
    for (int i = 0; i < 4; ++i) afr[i] = *(const bf16x8*)&As[wr + i * 16 + l15][klo];
#pragma unroll
    for (int j = 0; j < 4; ++j) bfr[j] = *(const bf16x8*)&Bs[wc + j * 16 + l15][klo];
#pragma unroll
    for (int i = 0; i < 4; ++i)
#pragma unroll
      for (int j = 0; j < 4; ++j)
        acc[i][j] = __builtin_amdgcn_mfma_f32_16x16x32_bf16(afr[i], bfr[j], acc[i][j], 0, 0, 0);
    __syncthreads();
    if (t + 1 < KT) { storeAB(); __syncthreads(); }
  }

  gemm_epilogue<EPI>(acc, mbase, nbase, wr, wc, l15, lhi, b0, res, outF, o0, o1, o2, b1, b2, ldo, scale);
}

// ---------------------------------------------------------------------------
// Temporal MFMA attention. Block = (instance, head): 1408*4 blocks, 4 waves.
__global__ __launch_bounds__(256)
void attn_t_k(const unsigned short* __restrict__ Qb, const unsigned short* __restrict__ Kb,
              const unsigned short* __restrict__ Vb, const unsigned short* __restrict__ kts,
              const unsigned short* __restrict__ vts, unsigned short* __restrict__ Ob) {
  __shared__ unsigned short Ps[128][134];  // 34.3 KB
  __shared__ unsigned short Vt[64][134];   // 17.2 KB (one d-half, transposed)
  const int tid = threadIdx.x;
  const int inst = blockIdx.x >> 2;
  const int h = blockIdx.x & 3;
  const int b = inst & (B_DIM - 1);
  const size_t rowbase = (size_t)inst * 120;
  const int hoff = h * 128;
  const int lane = tid & 63;
  const int w = tid >> 6;
  const int wr = w * 32;
  const int l15 = lane & 15;
  const int lhi = lane >> 4;

  auto stageV = [&](int half) {
    for (int e = tid; e < 2048; e += 256) {   // 128 key-cols x 16 us4 (zero-pad > 120)
      const int d4 = (e & 15) << 2;
      const int key = e >> 4;
      us4 v;
      if (key <= 120) {
        const unsigned short* src = (key == 0) ? (vts + b * 512) : (Vb + (rowbase + key - 1) * 512);
        v = *(const us4*)(src + hoff + half * 64 + d4);
      } else { v.x = 0; v.y = 0; v.z = 0; v.w = 0; }
      Vt[d4 + 0][key] = v.x; Vt[d4 + 1][key] = v.y; Vt[d4 + 2][key] = v.z; Vt[d4 + 3][key] = v.w;
    }
  };
  stageV(0);  // overlaps with QK^T below (no dependency until first barrier)

  bf16x8 qa[2][4];
#pragma unroll
  for (int i = 0; i < 2; ++i) {
    const int row = min(wr + i * 16 + l15, 119);
    const unsigned short* qp = Qb + (rowbase + row) * 512 + hoff;
#pragma unroll
    for (int kt = 0; kt < 4; ++kt)
      qa[i][kt] = *(const bf16x8*)(qp + kt * 32 + lhi * 8);
  }

  f32x4 acc[2][8] = {};
#pragma unroll
  for (int kt = 0; kt < 4; ++kt) {
    const int klo = kt * 32 + lhi * 8;
    bf16x8 kb[8];
#pragma unroll
    for (int j = 0; j < 8; ++j) {
      const int key = min(j * 16 + l15, 120);
      const unsigned short* kp = (key == 0) ? (kts + b * 512) : (Kb + (rowbase + key - 1) * 512);
      kb[j] = *(const bf16x8*)(kp + hoff + klo);
    }
#pragma unroll
    for (int i = 0; i < 2; ++i)
#pragma unroll
      for (int j = 0; j < 8; ++j)
        acc[i][j] = __builtin_amdgcn_mfma_f32_16x16x32_bf16(qa[i][kt], kb[j], acc[i][j], 0, 0, 0);
  }

  float rinv[2][4];
#pragma unroll
  for (int i = 0; i < 2; ++i)
#pragma unroll
    for (int q = 0; q < 4; ++q) {
      float m = -1e30f;
#pragma unroll
      for (int j = 0; j < 8; ++j)
        if (j * 16 + l15 <= 120) m = fmaxf(m, acc[i][j][q]);
#pragma unroll
      for (int mk = 1; mk < 16; mk <<= 1) m = fmaxf(m, __shfl_xor(m, mk, 64));
      float s = 0.f;
#pragma unroll
      for (int j = 0; j < 8; ++j) {
        const float e = (j * 16 + l15 <= 120) ? __expf(acc[i][j][q] - m) : 0.f;
        acc[i][j][q] = e; s += e;
      }
#pragma unroll
      for (int mk = 1; mk < 16; mk <<= 1) s += __shfl_xor(s, mk, 64);
      rinv[i][q] = 1.f / s;  // 1/sum deferred to the output store
    }

#pragma unroll
  for (int i = 0; i < 2; ++i)
#pragma unroll
    for (int j = 0; j < 8; ++j)
#pragma unroll
      for (int q = 0; q < 4; ++q)
        Ps[wr + i * 16 + lhi * 4 + q][j * 16 + l15] = f2b(acc[i][j][q]);

  __syncthreads();

#pragma unroll
  for (int half = 0; half < 2; ++half) {
    if (half == 1) {
      __syncthreads();
      stageV(1);
      __syncthreads();
    }
    f32x4 oac[2][4] = {};
#pragma unroll
    for (int kt = 0; kt < 4; ++kt) {
      const int klo = kt * 32 + lhi * 8;
      bf16x8 pa[2], vb[4];
#pragma unroll
      for (int i = 0; i < 2; ++i) pa[i] = *(const bf16x8*)&Ps[wr + i * 16 + l15][klo];
#pragma unroll
      for (int jd = 0; jd < 4; ++jd) vb[jd] = *(const bf16x8*)&Vt[jd * 16 + l15][klo];
#pragma unroll
      for (int i = 0; i < 2; ++i)
#pragma unroll
        for (int jd = 0; jd < 4; ++jd)
          oac[i][jd] = __builtin_amdgcn_mfma_f32_16x16x32_bf16(pa[i], vb[jd], oac[i][jd], 0, 0, 0);
    }
#pragma unroll
    for (int i = 0; i < 2; ++i)
#pragma unroll
      for (int q = 0; q < 4; ++q) {
        const int r = wr + i * 16 + lhi * 4 + q;
        if (r < 120) {
          const float sc = rinv[i][q];
#pragma unroll
          for (int jd = 0; jd < 4; ++jd)
            Ob[(rowbase + r) * 512 + hoff + half * 64 + jd * 16 + l15] = f2b(oac[i][jd][q] * sc);
        }
      }
  }
}

// ---------------------------------------------------------------------------
// Spatial MFMA attention. Block = (f,b) instance (7680 blocks), wave = head.
__global__ __launch_bounds__(256)
void attn_s_k(const unsigned short* __restrict__ Qb, const unsigned short* __restrict__ Kb,
              const unsigned short* __restrict__ Vb, const unsigned short* __restrict__ kts,
              const unsigned short* __restrict__ vts, unsigned short* __restrict__ Ob) {
  __shared__ unsigned short Ps[4][32][34];   // 8.7 KB
  __shared__ unsigned short Vt[4][128][34];  // 34.8 KB
  const int tid = threadIdx.x;
  const int inst = blockIdx.x;
  const int b = inst & (B_DIM - 1);
  const size_t rowbase = (size_t)inst * 22;
  const int lane = tid & 63;
  const int h = tid >> 6;  // wave = head
  const int l15 = lane & 15;
  const int lhi = lane >> 4;
  const int hoff = h * 128;

  for (int e = tid; e < 4096; e += 256) {   // 4 heads x 32 key-cols x 32 us4 (zero-pad)
    const int h2 = e >> 10;
    const int rem = e & 1023;
    const int key = rem >> 5;
    const int d4 = (rem & 31) << 2;
    us4 v;
    if (key <= 22) {
      const unsigned short* src = (key == 0) ? (vts + b * 512) : (Vb + (rowbase + key - 1) * 512);
      v = *(const us4*)(src + h2 * 128 + d4);
    } else { v.x = 0; v.y = 0; v.z = 0; v.w = 0; }
    Vt[h2][d4 + 0][key] = v.x; Vt[h2][d4 + 1][key] = v.y; Vt[h2][d4 + 2][key] = v.z; Vt[h2][d4 + 3][key] = v.w;
  }

  bf16x8 qa[2][4];
#pragma unroll
  for (int i = 0; i < 2; ++i) {
    const int row = min(i * 16 + l15, 21);
    const unsigned short* qp = Qb + (rowbase + row) * 512 + hoff;
#pragma unroll
    for (int kt = 0; kt < 4; ++kt)
      qa[i][kt] = *(const bf16x8*)(qp + kt * 32 + lhi * 8);
  }

  f32x4 acc[2][2] = {};
#pragma unroll
  for (int kt = 0; kt < 4; ++kt) {
    const int klo = kt * 32 + lhi * 8;
    bf16x8 kb[2];
#pragma unroll
    for (int j = 0; j < 2; ++j) {
      const int key = min(j * 16 + l15, 22);
      const unsigned short* kp = (key == 0) ? (kts + b * 512) : (Kb + (rowbase + key - 1) * 512);
      kb[j] = *(const bf16x8*)(kp + hoff + klo);
    }
#pragma unroll
    for (int i = 0; i < 2; ++i)
#pragma unroll
      for (int j = 0; j < 2; ++j)
        acc[i][j] = __builtin_amdgcn_mfma_f32_16x16x32_bf16(qa[i][kt], kb[j], acc[i][j], 0, 0, 0);
  }

  float rinv[2][4];
#pragma unroll
  for (int i = 0; i < 2; ++i)
#pragma unroll
    for (int q = 0; q < 4; ++q) {
      float m = -1e30f;
#pragma unroll
      for (int j = 0; j < 2; ++j)
        if (j * 16 + l15 <= 22) m = fmaxf(m, acc[i][j][q]);
#pragma unroll
      for (int mk = 1; mk < 16; mk <<= 1) m = fmaxf(m, __shfl_xor(m, mk, 64));
      float s = 0.f;
#pragma unroll
      for (int j = 0; j < 2; ++j) {
        const float e = (j * 16 + l15 <= 22) ? __expf(acc[i][j][q] - m) : 0.f;
        acc[i][j][q] = e; s += e;
      }
#pragma unroll
      for (int mk = 1; mk < 16; mk <<= 1) s += __shfl_xor(s, mk, 64);
      rinv[i][q] = 1.f / s;
    }

#pragma unroll
  for (int i = 0; i < 2; ++i)
#pragma unroll
    for (int j = 0; j < 2; ++j)
#pragma unroll
      for (int q = 0; q < 4; ++q)
        Ps[h][i * 16 + lhi * 4 + q][j * 16 + l15] = f2b(acc[i][j][q]);

  __syncthreads();

  f32x4 oac[2][8] = {};
  {
    const int klo = lhi * 8;
    bf16x8 pa[2];
#pragma unroll
    for (int i = 0; i < 2; ++i) pa[i] = *(const bf16x8*)&Ps[h][i * 16 + l15][klo];
#pragma unroll
    for (int jd = 0; jd < 8; ++jd) {
      const bf16x8 vb = *(const bf16x8*)&Vt[h][jd * 16 + l15][klo];
#pragma unroll
      for (int i = 0; i < 2; ++i)
        oac[i][jd] = __builtin_amdgcn_mfma_f32_16x16x32_bf16(pa[i], vb, oac[i][jd], 0, 0, 0);
    }
  }

#pragma unroll
  for (int i = 0; i < 2; ++i)
#pragma unroll
    for (int q = 0; q < 4; ++q) {
      const int r = i * 16 + lhi * 4 + q;
      if (r < 22) {
        const float sc = rinv[i][q];
#pragma unroll
        for (int jd = 0; jd < 8; ++jd)
          Ob[(rowbase + r) * 512 + hoff + jd * 16 + l15] = f2b(oac[i][jd][q] * sc);
      }
    }
}

// ---------------------------------------------------------------------------
// Row norm (torch.std semantics: ddof=1, eps added to sd), fused layout transpose.
// mode 0: identity; mode 1: (F,B,J)->(J,B,F); mode 2: (J,B,F)->(F,B,J)
// Optional bf16 copy (outB) for downstream GEMM A-operands.
__global__ __launch_bounds__(64)
void norm_k(const float* __restrict__ in, float* __restrict__ out,
            unsigned short* __restrict__ outB,
            const float* __restrict__ ga, const float* __restrict__ gb, const int mode) {
  const int r = blockIdx.x;
  const int lane = threadIdx.x;
  const float* row = in + (size_t)r * 512;
  const float4 v0 = *(const float4*)&row[lane * 4];
  const float4 v1 = *(const float4*)&row[256 + lane * 4];
  float s = v0.x + v0.y + v0.z + v0.w + v1.x + v1.y + v1.z + v1.w;
  float ss = v0.x * v0.x + v0.y * v0.y + v0.z * v0.z + v0.w * v0.w
           + v1.x * v1.x + v1.y * v1.y + v1.z * v1.z + v1.w * v1.w;
#pragma unroll
  for (int m = 1; m < 64; m <<= 1) { s += __shfl_xor(s, m, 64); ss += __shfl_xor(ss, m, 64); }
  const float mean = s * (1.f / 512.f);
  const float var = (ss - 512.f * mean * mean) * (1.f / 511.f);
  const float inv = 1.f / (sqrtf(fmaxf(var, 0.f)) + 1e-6f);
  int ro;
  if (mode == 0) ro = r;
  else if (mode == 1) {
    const int f = r / (B_DIM * J_DIM);
    const int bb = (r / J_DIM) % B_DIM;
    const int j = r % J_DIM;
    ro = (j * B_DIM + bb) * F_DIM + f;
  } else {
    const int j = r / (B_DIM * F_DIM);
    const int bb = (r / F_DIM) % B_DIM;
    const int f = r % F_DIM;
    ro = (f * B_DIM + bb) * J_DIM + j;
  }
  const float4 g0 = *(const float4*)&ga[lane * 4];
  const float4 g1 = *(const float4*)&ga[256 + lane * 4];
  const float4 h0 = *(const float4*)&gb[lane * 4];
  const float4 h1 = *(const float4*)&gb[256 + lane * 4];
  float4 y0, y1;
  y0.x = g0.x * (v0.x - mean) * inv + h0.x;
  y0.y = g0.y * (v0.y - mean) * inv + h0.y;
  y0.z = g0.z * (v0.z - mean) * inv + h0.z;
  y0.w = g0.w * (v0.w - mean) * inv + h0.w;
  y1.x = g1.x * (v1.x - mean) * inv + h1.x;
  y1.y = g1.y * (v1.y - mean) * inv + h1.y;
  y1.z = g1.z * (v1.z - mean) * inv + h1.z;
  y1.w = g1.w * (v1.w - mean) * inv + h1.w;
  float* orow = out + (size_t)ro * 512;
  *(float4*)&orow[lane * 4] = y0;
  *(float4*)&orow[256 + lane * 4] = y1;
  if (outB) {
    us4 a, b;
    a.x = f2b(y0.x); a.y = f2b(y0.y); a.z = f2b(y0.z); a.w = f2b(y0.w);
    b.x = f2b(y1.x); b.y = f2b(y1.y); b.z = f2b(y1.z); b.w = f2b(y1.w);
    *(us4*)&outB[(size_t)ro * 512 + lane * 4] = a;
    *(us4*)&outB[(size_t)ro * 512 + 256 + lane * 4] = b;
  }
}

// ---------------------------------------------------------------------------
extern "C" void kernel_launch(void* const* d_in, const int* in_sizes, int n_in,
                              void* d_out, int out_size, void* d_ws, size_t ws_size,
                              hipStream_t stream) {
  const float* x   = (const float*)d_in[0];
  const float* tse = (const float*)d_in[1];
  const float* sWq = (const float*)d_in[5];  const float* sbq = (const float*)d_in[6];
  const float* sWk = (const float*)d_in[7];  const float* sbk = (const float*)d_in[8];
  const float* sWv = (const float*)d_in[9];  const float* sbv = (const float*)d_in[10];
  const float* sWo = (const float*)d_in[11]; const float* sbo = (const float*)d_in[12];
  const float* tWq = (const float*)d_in[13]; const float* tbq = (const float*)d_in[14];
  const float* tWk = (const float*)d_in[15]; const float* tbk = (const float*)d_in[16];
  const float* tWv = (const float*)d_in[17]; const float* tbv = (const float*)d_in[18];
  const float* tWo = (const float*)d_in[19]; const float* tbo = (const float*)d_in[20];
  const float* ffW1 = (const float*)d_in[21]; const float* ffb1 = (const float*)d_in[22];
  const float* ffW2 = (const float*)d_in[23]; const float* ffb2 = (const float*)d_in[24];
  const float* n1a = (const float*)d_in[25]; const float* n1b = (const float*)d_in[26];
  const float* n2a = (const float*)d_in[27]; const float* n2b = (const float*)d_in[28];
  const float* n3a = (const float*)d_in[29]; const float* n3b = (const float*)d_in[30];

  char* p = (char*)d_ws;
  auto carve = [&](size_t bytes) { void* r = (void*)p; p += (bytes + 255) & ~(size_t)255; return r; };

  unsigned short* sQKVt = (unsigned short*)carve((size_t)3 * 512 * 512 * 2);
  unsigned short* sOT   = (unsigned short*)carve((size_t)512 * 512 * 2);
  unsigned short* tQKVt = (unsigned short*)carve((size_t)3 * 512 * 512 * 2);
  unsigned short* tOT   = (unsigned short*)carve((size_t)512 * 512 * 2);
  unsigned short* W1T   = (unsigned short*)carve((size_t)2048 * 512 * 2);
  unsigned short* W2T   = (unsigned short*)carve((size_t)512 * 2048 * 2);
  unsigned short* ktss  = (unsigned short*)carve((size_t)64 * 512 * 2);
  unsigned short* vtss  = (unsigned short*)carve((size_t)64 * 512 * 2);
  unsigned short* ktst  = (unsigned short*)carve((size_t)64 * 512 * 2);
  unsigned short* vtst  = (unsigned short*)carve((size_t)64 * 512 * 2);
  unsigned short* Qb    = (unsigned short*)carve((size_t)M_TOK * 512 * 2);
  float*          Rbuf  = (float*)carve((size_t)M_TOK * 512 * 4);

  unsigned short* Kb = (unsigned short*)d_out;           // K/V bf16 alias d_out while dead as f32
  unsigned short* Vb = Kb + (size_t)M_TOK * 512;
  float* outF = (float*)d_out;

  const bool bigws = ws_size >= (size_t)873725952ull;
  unsigned short* Hb  = nullptr;   // [M][1024] bf16 (FF hidden); early life: xb | rb1
  unsigned short* xb  = nullptr;   // bf16 cast of x        (dead after spatial QKV)
  unsigned short* rb1 = nullptr;   // bf16 of norm1 output  (dead after temporal QKV)
  if (bigws) {
    Hb = (unsigned short*)carve((size_t)M_TOK * 1024 * 2);
    xb = Hb;
    rb1 = Hb + (size_t)M_TOK * 512;
  }

  const float QSCALE = 0.08838834764831845f; // 1/sqrt(128)

  {
    dim3 tb(32, 8);
    tcast_k<<<dim3(16, 16), tb, 0, stream>>>(sWq, sQKVt, 512, 512);
    tcast_k<<<dim3(16, 16), tb, 0, stream>>>(sWk, sQKVt + 262144, 512, 512);
    tcast_k<<<dim3(16, 16), tb, 0, stream>>>(sWv, sQKVt + 524288, 512, 512);
    tcast_k<<<dim3(16, 16), tb, 0, stream>>>(sWo, sOT, 512, 512);
    tcast_k<<<dim3(16, 16), tb, 0, stream>>>(tWq, tQKVt, 512, 512);
    tcast_k<<<dim3(16, 16), tb, 0, stream>>>(tWk, tQKVt + 262144, 512, 512);
    tcast_k<<<dim3(16, 16), tb, 0, stream>>>(tWv, tQKVt + 524288, 512, 512);
    tcast_k<<<dim3(16, 16), tb, 0, stream>>>(tWo, tOT, 512, 512);
    tcast_k<<<dim3(64, 16), tb, 0, stream>>>(ffW1, W1T, 512, 2048);
    tcast_k<<<dim3(16, 64), tb, 0, stream>>>(ffW2, W2T, 2048, 512);
  }
  tsproj_k<<<B_DIM, 256, 0, stream>>>(tse, sWk, sbk, ktss);
  tsproj_k<<<B_DIM, 256, 0, stream>>>(tse, sWv, sbv, vtss);
  tsproj_k<<<B_DIM, 256, 0, stream>>>(tse, tWk, tbk, ktst);
  tsproj_k<<<B_DIM, 256, 0, stream>>>(tse, tWv, tbv, vtst);

  const int MT = M_TOK / 128; // 1320 (all GEMM grids are %8==0)

  // ---- spatial attention ----
  if (bigws) {
    cast_k<<<2048, 256, 0, stream>>>(x, xb, M_TOK * 512 / 8);
    gemm_k<EPI_QKV><<<12 * MT, 256, 0, stream>>>(
        xb, sQKVt, sbq, sbk, sbv, nullptr, nullptr, Qb, Kb, Vb, 512, 512, 512, 512, 12, QSCALE);
  } else {
    gemmf_k<EPI_QKV><<<12 * MT, 256, 0, stream>>>(
        x, sQKVt, sbq, sbk, sbv, nullptr, nullptr, Qb, Kb, Vb, 512, 512, 512, 512, 12, QSCALE);
  }
  attn_s_k<<<dim3(F_DIM * B_DIM), 256, 0, stream>>>(Qb, Kb, Vb, ktss, vtss, Qb);
  gemm_k<EPI_RES><<<4 * MT, 256, 0, stream>>>(
      Qb, sOT, sbo, nullptr, nullptr, x, outF, nullptr, nullptr, nullptr, 512, 512, 512, 512, 4, 1.f);
  norm_k<<<M_TOK, 64, 0, stream>>>(outF, Rbuf, bigws ? rb1 : nullptr, n1a, n1b, 1);

  // ---- temporal attention ----
  if (bigws)
    gemm_k<EPI_QKV><<<12 * MT, 256, 0, stream>>>(
        rb1, tQKVt, tbq, tbk, tbv, nullptr, nullptr, Qb, Kb, Vb, 512, 512, 512, 512, 12, QSCALE);
  else
    gemmf_k<EPI_QKV><<<12 * MT, 256, 0, stream>>>(
        Rbuf, tQKVt, tbq, tbk, tbv, nullptr, nullptr, Qb, Kb, Vb, 512, 512, 512, 512, 12, QSCALE);
  attn_t_k<<<dim3(J_DIM * B_DIM * H_DIM), 256, 0, stream>>>(Qb, Kb, Vb, ktst, vtst, Qb);
  gemm_k<EPI_RES><<<4 * MT, 256, 0, stream>>>(
      Qb, tOT, tbo, nullptr, nullptr, Rbuf, outF, nullptr, nullptr, nullptr, 512, 512, 512, 512, 4, 1.f);
  // norm2 bf16 copy -> Qb (dead after temporal O-proj); feeds FF gelu A
  norm_k<<<M_TOK, 64, 0, stream>>>(outF, Rbuf, bigws ? Qb : nullptr, n2a, n2b, 2);

  // ---- feed-forward ----
  if (bigws) {
    for (int c = 0; c < 2; ++c) {
      gemm_k<EPI_GELU><<<8 * MT, 256, 0, stream>>>(
          Qb, W1T + (size_t)c * 1024 * 512, ffb1 + c * 1024, nullptr, nullptr,
          nullptr, nullptr, Hb, nullptr, nullptr, 512, 512, 1024, 512, 8, 1.f);
      if (c == 0)
        gemm_k<EPI_RES><<<4 * MT, 256, 0, stream>>>(
            Hb, W2T + c * 1024, ffb2, nullptr, nullptr, Rbuf, outF,
            nullptr, nullptr, nullptr, 1024, 2048, 512, 1024, 4, 1.f);
      else
        gemm_k<EPI_ACC><<<4 * MT, 256, 0, stream>>>(
            Hb, W2T + c * 1024, nullptr, nullptr, nullptr, nullptr, outF,
            nullptr, nullptr, nullptr, 1024, 2048, 512, 1024, 4, 1.f);
    }
  } else {
    for (int c = 0; c < 4; ++c) {
      gemmf_k<EPI_GELU><<<4 * MT, 256, 0, stream>>>(
          Rbuf, W1T + (size_t)c * 512 * 512, ffb1 + c * 512, nullptr, nullptr,
          nullptr, nullptr, Qb, nullptr, nullptr, 512, 512, 512, 512, 4, 1.f);
      if (c == 0)
        gemm_k<EPI_RES><<<4 * MT, 256, 0, stream>>>(
            Qb, W2T + c * 512, ffb2, nullptr, nullptr, Rbuf, outF,
            nullptr, nullptr, nullptr, 512, 2048, 512, 512, 4, 1.f);
      else
        gemm_k<EPI_ACC><<<4 * MT, 256, 0, stream>>>(
            Qb, W2T + c * 512, nullptr, nullptr, nullptr, nullptr, outF,
            nullptr, nullptr, nullptr, 512, 2048, 512, 512, 4, 1.f);
    }
  }

  norm_k<<<M_TOK, 64, 0, stream>>>(outF, outF, nullptr, n3a, n3b, 0);
}